// Round 1
// baseline (12308.823 us; speedup 1.0000x reference)
//
#include <hip/hip_runtime.h>
#include <cstddef>
#include <cstdint>

#define T_STEPS 200
#define BB 64
#define SS 8
#define DD 128
#define RR 512
#define ZZ 256
#define HH 1024
#define DT 0.05f
#define SQRT_DT 0.22360679774997896f
#define LOG2PIF 1.8378770664093453f

typedef __attribute__((ext_vector_type(8))) short bf16x8;
typedef __attribute__((ext_vector_type(4))) float f32x4;
#define MFMA __builtin_amdgcn_mfma_f32_16x16x32_bf16

static __device__ __forceinline__ unsigned short f2bf(float x) {
    unsigned int u = __builtin_bit_cast(unsigned int, x);
    u += 0x7fffu + ((u >> 16) & 1u);
    return (unsigned short)(u >> 16);
}
static __device__ __forceinline__ float bf2f(unsigned short h) {
    unsigned int u = ((unsigned int)h) << 16;
    return __builtin_bit_cast(float, u);
}
static __device__ __forceinline__ float fast_tanh(float x) {
    // 1 - 2/(e^{2x}+1); robust at +-inf
    float e = __expf(2.0f * x);
    return 1.0f - 2.0f / (e + 1.0f);
}

// ---------------------------------------------------------------------------
// Pack a row-major fp32 weight matrix W[K][N] into bf16 MFMA B-fragment order:
// elem layout: [nt][ks][lane][i]  with  n = nt*16 + (lane&15),
//                                       k = ks*32 + (lane>>4)*8 + i
// so the scan/precompute kernels read perfectly-coalesced 16B per lane.
// ---------------------------------------------------------------------------
__global__ void pack_w(const float* __restrict__ src, int K, int N,
                       unsigned short* __restrict__ dst) {
    int total = (K >> 5) * (N >> 4) * 64;
    int p = blockIdx.x * blockDim.x + threadIdx.x;
    if (p >= total) return;
    int lane = p & 63;
    int ksteps = K >> 5;
    int ks = (p >> 6) % ksteps;
    int nt = p / (ksteps << 6);
    int n = (nt << 4) + (lane & 15);
    int k0 = (ks << 5) + ((lane >> 4) << 3);
    uint4 u4;
    unsigned short* tmp = reinterpret_cast<unsigned short*>(&u4);
    for (int i = 0; i < 8; ++i) tmp[i] = f2bf(src[(size_t)(k0 + i) * N + n]);
    *reinterpret_cast<uint4*>(dst + (size_t)p * 8) = u4;
}

// Mt[t,b] = mean over D of M[t,b,:]
__global__ void mt_kernel(const float* __restrict__ M, float* __restrict__ Mt) {
    int wv = (blockIdx.x * blockDim.x + threadIdx.x) >> 6;
    int lane = threadIdx.x & 63;
    if (wv >= T_STEPS * BB) return;
    const float* row = M + (size_t)wv * DD;
    float s = row[lane] + row[lane + 64];
    for (int off = 32; off; off >>= 1) s += __shfl_down(s, off, 64);
    if (lane == 0) Mt[wv] = s * (1.0f / DD);
}

// ---------------------------------------------------------------------------
// Precompute (parallel over T*B rows, 16 rows per block):
//   HprojQ  = h    @ drift_w1[:R] + drift_b1          (bf16)
//   HpprojQ = hpos @ drift_w1[:R] + drift_b1          (bf16)
//   PprojQ  = h    @ p_w1[:R]     + p_b1              (bf16)
//   DiffQ   = exp(relu(h@diff_w1+b1) @ diff_w2 + b2)  (fp32)
// ---------------------------------------------------------------------------
#define PC_GEMM_1024(Asrc, Bp, biasArr, EMIT)                                    \
    {                                                                            \
        f32x4 acc[16];                                                           \
        f32x4 z4 = {0.f, 0.f, 0.f, 0.f};                                        \
        for (int ntl = 0; ntl < 16; ++ntl) acc[ntl] = z4;                        \
        for (int ks = 0; ks < 16; ++ks) {                                        \
            bf16x8 a = *(const bf16x8*)&Asrc[l][(ks << 5) + (q << 3)];           \
            for (int ntl = 0; ntl < 16; ++ntl) {                                 \
                int ntg = (w << 4) + ntl;                                        \
                bf16x8 bb = *(const bf16x8*)(Bp +                                \
                             (((size_t)ntg * 16 + ks) * 64 + lane) * 8);         \
                acc[ntl] = MFMA(a, bb, acc[ntl], 0, 0, 0);                       \
            }                                                                    \
        }                                                                        \
        for (int ntl = 0; ntl < 16; ++ntl) {                                     \
            int n = (((w << 4) + ntl) << 4) + l;                                 \
            float bv = biasArr[n];                                               \
            for (int i = 0; i < 4; ++i) {                                        \
                int rr = (q << 2) + i;                                           \
                float v = acc[ntl][i] + bv;                                      \
                EMIT;                                                            \
            }                                                                    \
        }                                                                        \
    }

__global__ __launch_bounds__(256)
void precompute_kernel(const float* __restrict__ h, const float* __restrict__ hpos,
                       const float* __restrict__ b1d, const float* __restrict__ b1p,
                       const float* __restrict__ b1f, const float* __restrict__ b2f,
                       const unsigned short* __restrict__ W1h_p,
                       const unsigned short* __restrict__ PW1h_p,
                       const unsigned short* __restrict__ DW1_p,
                       const unsigned short* __restrict__ DW2_p,
                       unsigned short* __restrict__ HprojQ,
                       unsigned short* __restrict__ HpprojQ,
                       unsigned short* __restrict__ PprojQ,
                       float* __restrict__ DiffQ) {
    __shared__ unsigned short Ahh[16][RR + 8];
    __shared__ unsigned short Ahp[16][RR + 8];
    __shared__ unsigned short Adh[16][HH + 8];
    const int tid = threadIdx.x;
    const int lane = tid & 63;
    const int w = tid >> 6;   // 4 waves
    const int q = lane >> 4;
    const int l = lane & 15;
    const int r0 = blockIdx.x << 4;   // 16 flat (t*B+b) rows per block

    for (int idx = tid; idx < (RR << 4); idx += 256) {
        int r = idx >> 9, c = idx & (RR - 1);
        Ahh[r][c] = f2bf(h[(size_t)(r0 + r) * RR + c]);
        Ahp[r][c] = f2bf(hpos[(size_t)(r0 + r) * RR + c]);
    }
    __syncthreads();

    PC_GEMM_1024(Ahh, W1h_p,  b1d, (HprojQ [(size_t)(r0 + rr) * HH + n] = f2bf(v)));
    PC_GEMM_1024(Ahp, W1h_p,  b1d, (HpprojQ[(size_t)(r0 + rr) * HH + n] = f2bf(v)));
    PC_GEMM_1024(Ahh, PW1h_p, b1p, (PprojQ [(size_t)(r0 + rr) * HH + n] = f2bf(v)));
    PC_GEMM_1024(Ahh, DW1_p,  b1f, (Adh[rr][n] = f2bf(fmaxf(v, 0.f))));
    __syncthreads();

    {   // diffusion layer 2: Adh[16,1024] @ diff_w2 -> exp -> DiffQ
        f32x4 acc[4];
        f32x4 z4 = {0.f, 0.f, 0.f, 0.f};
        for (int ntl = 0; ntl < 4; ++ntl) acc[ntl] = z4;
        for (int ks = 0; ks < 32; ++ks) {
            bf16x8 a = *(const bf16x8*)&Adh[l][(ks << 5) + (q << 3)];
            for (int ntl = 0; ntl < 4; ++ntl) {
                int ntg = (w << 2) + ntl;
                bf16x8 bb = *(const bf16x8*)(DW2_p +
                             (((size_t)ntg * 32 + ks) * 64 + lane) * 8);
                acc[ntl] = MFMA(a, bb, acc[ntl], 0, 0, 0);
            }
        }
        for (int ntl = 0; ntl < 4; ++ntl) {
            int n = (((w << 2) + ntl) << 4) + l;
            float bv = b2f[n];
            for (int i = 0; i < 4; ++i) {
                int rr = (q << 2) + i;
                DiffQ[(size_t)(r0 + rr) * ZZ + n] = __expf(acc[ntl][i] + bv);
            }
        }
    }
}

// ---------------------------------------------------------------------------
// Sequential scan: 64 blocks (one per batch b), 1024 threads (16 waves).
// Per step, 4 MFMA stages, all row-local to the block -> only __syncthreads.
// A-operands in LDS (16-row tiles, rows 8..15 zero-padded where M=8).
// B-operands streamed from L2 in packed fragment order.
// ---------------------------------------------------------------------------
__global__ __launch_bounds__(1024)
void scan_kernel(const float* __restrict__ X, const float* __restrict__ cov,
                 const float* __restrict__ noise,
                 const float* __restrict__ b2d, const float* __restrict__ b2p,
                 const float* __restrict__ cw1, const float* __restrict__ cb1,
                 const float* __restrict__ cw2, const float* __restrict__ cb2,
                 const unsigned short* __restrict__ W1z_p,
                 const unsigned short* __restrict__ W2_p,
                 const unsigned short* __restrict__ PW1z_p,
                 const unsigned short* __restrict__ PW2_p,
                 const unsigned short* __restrict__ HprojQ,
                 const unsigned short* __restrict__ HpprojQ,
                 const unsigned short* __restrict__ PprojQ,
                 const float* __restrict__ DiffQ,
                 const float* __restrict__ MtQ,
                 float* __restrict__ out) {
    __shared__ unsigned short Az[16][ZZ + 8];   // z (bf16), rows 8..15 = 0
    __shared__ unsigned short Ah[16][HH + 8];   // drift hidden: rows 0-7 prior, 8-15 poster
    __shared__ unsigned short Ap[16][HH + 8];   // decoder hidden, rows 8..15 = 0
    __shared__ float zf[SS][ZZ];                // fp32 master state
    __shared__ unsigned short Hp_t[HH], Hpp_t[HH], Pp_t[HH];
    __shared__ float Diff_t[ZZ], invDiff_t[ZZ];
    __shared__ float Xt_s[DD];
    __shared__ float b2d_s[ZZ], b2p_s[DD];
    __shared__ float red[16][2];
    __shared__ float ch[64];

    const int tid = threadIdx.x;
    const int lane = tid & 63;
    const int w = tid >> 6;   // 16 waves
    const int q = lane >> 4;
    const int l = lane & 15;
    const int b = blockIdx.x;

    // --- prologue: zero pads, biases, z0 = tanh(MLP(cov)) ---
    for (int idx = tid; idx < 16 * (ZZ + 8); idx += 1024) ((unsigned short*)Az)[idx] = 0;
    for (int idx = tid; idx < 16 * (HH + 8); idx += 1024) ((unsigned short*)Ap)[idx] = 0;
    if (tid < ZZ) b2d_s[tid] = b2d[tid];
    if (tid < DD) b2p_s[tid] = b2p[tid];
    if (tid < 64) {
        float s = cb1[tid];
        for (int c = 0; c < 16; ++c) s += cov[b * 16 + c] * cw1[c * 64 + tid];
        ch[tid] = fmaxf(s, 0.f);
    }
    __syncthreads();
    if (tid < ZZ) {
        float v = cb2[tid];
        for (int j = 0; j < 64; ++j) v += ch[j] * cw2[j * ZZ + tid];
        v = fast_tanh(v);
        unsigned short hv = f2bf(v);
        for (int s = 0; s < SS; ++s) { zf[s][tid] = v; Az[s][tid] = hv; }
    }

    float kld_acc = 0.f, recon_acc = 0.f;

    for (int t = 0; t < T_STEPS; ++t) {
        const size_t tb = (size_t)t * BB + b;
        // stage per-step vectors
        Hp_t[tid]  = HprojQ [tb * HH + tid];
        Hpp_t[tid] = HpprojQ[tb * HH + tid];
        Pp_t[tid]  = PprojQ [tb * HH + tid];
        if (tid < ZZ) {
            float d = DiffQ[tb * ZZ + tid];
            Diff_t[tid] = d;
            invDiff_t[tid] = 1.0f / d;
        }
        if (tid < DD) Xt_s[tid] = X[tb * DD + tid];
        __syncthreads();   // staging ready; Az/zf from previous step final

        // ---- G1: zpart = z @ W1z ; hidden = relu(Hproj/Hpproj + zpart) -> Ah
        {
            f32x4 acc[4];
            f32x4 z4 = {0.f, 0.f, 0.f, 0.f};
            for (int ntl = 0; ntl < 4; ++ntl) acc[ntl] = z4;
            for (int ks = 0; ks < 8; ++ks) {
                bf16x8 a = *(const bf16x8*)&Az[l][(ks << 5) + (q << 3)];
                for (int ntl = 0; ntl < 4; ++ntl) {
                    bf16x8 bb = *(const bf16x8*)(W1z_p +
                                 (((size_t)(w * 4 + ntl) * 8 + ks) * 64 + lane) * 8);
                    acc[ntl] = MFMA(a, bb, acc[ntl], 0, 0, 0);
                }
            }
            for (int ntl = 0; ntl < 4; ++ntl) {
                int n = ((w * 4 + ntl) << 4) + l;
                float hb = bf2f(Hp_t[n]);
                float hpb = bf2f(Hpp_t[n]);
                for (int i = 0; i < 4; ++i) {
                    float own = acc[ntl][i];                 // zpart rows 0-7 (q<2), 0 (q>=2)
                    float other = __shfl_xor(own, 32, 64);   // partner's zpart
                    float zp = (q < 2) ? own : other;
                    float base = (q < 2) ? hb : hpb;
                    int rr = (q << 2) + i;                   // 0-7 prior, 8-15 poster
                    Ah[rr][n] = f2bf(fmaxf(base + zp, 0.f));
                }
            }
        }
        __syncthreads();

        // ---- G2: hidden @ W2 -> drift pre-acts; z_new (raw); kld
        {
            f32x4 acc = {0.f, 0.f, 0.f, 0.f};
            for (int ks = 0; ks < 32; ++ks) {
                bf16x8 a = *(const bf16x8*)&Ah[l][(ks << 5) + (q << 3)];
                bf16x8 bb = *(const bf16x8*)(W2_p +
                             (((size_t)w * 32 + ks) * 64 + lane) * 8);
                acc = MFMA(a, bb, acc, 0, 0, 0);
            }
            int n = (w << 4) + l;
            float bias = b2d_s[n];
            float dif = Diff_t[n], idif = invDiff_t[n];
            for (int i = 0; i < 4; ++i) {
                float pre = acc[i] + bias;                  // q<2: prior, q>=2: poster
                float other = __shfl_xor(pre, 32, 64);
                float prior_pre  = (q < 2) ? pre : other;
                float poster_pre = (q < 2) ? other : pre;
                float pr = 0.1f * fast_tanh(prior_pre);
                float po = 0.1f * fast_tanh(poster_pre);
                if (q < 2) {
                    int s = (q << 2) + i;
                    float err = (pr - po) * idif;
                    kld_acc += err * err;
                    float eps = noise[(tb * SS + s) * ZZ + n];
                    zf[s][n] = zf[s][n] + DT * po + SQRT_DT * dif * eps;
                }
            }
        }
        __syncthreads();

        // ---- per-row min-max normalize (wave s handles row s)
        if (w < SS) {
            float v0 = zf[w][lane], v1 = zf[w][lane + 64];
            float v2 = zf[w][lane + 128], v3 = zf[w][lane + 192];
            float mn = fminf(fminf(v0, v1), fminf(v2, v3));
            float mx = fmaxf(fmaxf(v0, v1), fmaxf(v2, v3));
            for (int off = 32; off; off >>= 1) {
                mn = fminf(mn, __shfl_xor(mn, off, 64));
                mx = fmaxf(mx, __shfl_xor(mx, off, 64));
            }
            float sc = 1.0f / (mx - mn);
            v0 = (v0 - mn) * sc; v1 = (v1 - mn) * sc;
            v2 = (v2 - mn) * sc; v3 = (v3 - mn) * sc;
            zf[w][lane] = v0; zf[w][lane + 64] = v1;
            zf[w][lane + 128] = v2; zf[w][lane + 192] = v3;
            Az[w][lane] = f2bf(v0); Az[w][lane + 64] = f2bf(v1);
            Az[w][lane + 128] = f2bf(v2); Az[w][lane + 192] = f2bf(v3);
        }
        __syncthreads();

        // ---- G3: z_new @ p_w1z ; hidden_p = relu(Pproj + .) -> Ap rows 0-7
        {
            f32x4 acc[4];
            f32x4 z4 = {0.f, 0.f, 0.f, 0.f};
            for (int ntl = 0; ntl < 4; ++ntl) acc[ntl] = z4;
            for (int ks = 0; ks < 8; ++ks) {
                bf16x8 a = *(const bf16x8*)&Az[l][(ks << 5) + (q << 3)];
                for (int ntl = 0; ntl < 4; ++ntl) {
                    bf16x8 bb = *(const bf16x8*)(PW1z_p +
                                 (((size_t)(w * 4 + ntl) * 8 + ks) * 64 + lane) * 8);
                    acc[ntl] = MFMA(a, bb, acc[ntl], 0, 0, 0);
                }
            }
            if (q < 2) {
                for (int ntl = 0; ntl < 4; ++ntl) {
                    int n = ((w * 4 + ntl) << 4) + l;
                    float pb = bf2f(Pp_t[n]);
                    for (int i = 0; i < 4; ++i) {
                        int rr = (q << 2) + i;
                        Ap[rr][n] = f2bf(fmaxf(pb + acc[ntl][i], 0.f));
                    }
                }
            }
        }
        __syncthreads();

        // ---- G4 (waves 0-7): hidden_p @ p_w2 -> p ; recon accumulation
        if (w < 8) {
            f32x4 acc = {0.f, 0.f, 0.f, 0.f};
            for (int ks = 0; ks < 32; ++ks) {
                bf16x8 a = *(const bf16x8*)&Ap[l][(ks << 5) + (q << 3)];
                bf16x8 bb = *(const bf16x8*)(PW2_p +
                             (((size_t)w * 32 + ks) * 64 + lane) * 8);
                acc = MFMA(a, bb, acc, 0, 0, 0);
            }
            if (q < 2) {
                int n = (w << 4) + l;
                float xm = Xt_s[n];
                float bias = b2p_s[n];
                float mt = MtQ[tb] * 0.125f;   // mean over S
                float local = 0.f;
                for (int i = 0; i < 4; ++i) {
                    float p = acc[i] + bias;
                    float dd = xm - p;
                    local += 0.5f * (LOG2PIF + dd * dd);
                }
                recon_acc += local * mt;
            }
        }
        // next iteration's staging writes (Hp_t/...) are not read by G4: safe.
    }
    __syncthreads();

    // z_final
    for (int idx = tid; idx < SS * ZZ; idx += 1024) {
        int s = idx >> 8, n = idx & 255;
        out[((size_t)b * SS + s) * ZZ + n] = zf[s][n];
    }
    // loss reduction
    float k = kld_acc, r = recon_acc;
    for (int off = 32; off; off >>= 1) {
        k += __shfl_down(k, off, 64);
        r += __shfl_down(r, off, 64);
    }
    if (lane == 0) { red[w][0] = k; red[w][1] = r; }
    __syncthreads();
    if (tid == 0) {
        float K = 0.f, R = 0.f;
        for (int i = 0; i < 16; ++i) { K += red[i][0]; R += red[i][1]; }
        float kc = K * (0.5f * DT / (SS * BB));
        float rc = R * (1.0f / BB);
        float* lossp = out + (size_t)BB * SS * ZZ;
        atomicAdd(lossp + 0, rc + kc);
        atomicAdd(lossp + 1, rc);
        atomicAdd(lossp + 2, kc);
    }
}

extern "C" void kernel_launch(void* const* d_in, const int* in_sizes, int n_in,
                              void* d_out, int out_size, void* d_ws, size_t ws_size,
                              hipStream_t stream) {
    (void)in_sizes; (void)n_in; (void)ws_size;
    const float* X         = (const float*)d_in[0];
    const float* M         = (const float*)d_in[1];
    const float* cov       = (const float*)d_in[2];
    const float* path_h    = (const float*)d_in[3];
    const float* path_hpos = (const float*)d_in[4];
    const float* noise     = (const float*)d_in[5];
    const float* drift_w1  = (const float*)d_in[6];
    const float* drift_b1  = (const float*)d_in[7];
    const float* drift_w2  = (const float*)d_in[8];
    const float* drift_b2  = (const float*)d_in[9];
    const float* diff_w1   = (const float*)d_in[10];
    const float* diff_b1   = (const float*)d_in[11];
    const float* diff_w2   = (const float*)d_in[12];
    const float* diff_b2   = (const float*)d_in[13];
    const float* p_w1      = (const float*)d_in[14];
    const float* p_b1      = (const float*)d_in[15];
    const float* p_w2      = (const float*)d_in[16];
    const float* p_b2      = (const float*)d_in[17];
    const float* cov_w1    = (const float*)d_in[18];
    const float* cov_b1    = (const float*)d_in[19];
    const float* cov_w2    = (const float*)d_in[20];
    const float* cov_b2    = (const float*)d_in[21];

    char* ws = (char*)d_ws;
    size_t off = 0;
    auto alloc = [&](size_t bytes) {
        void* p = ws + off;
        off = (off + bytes + 255) & ~(size_t)255;
        return p;
    };
    unsigned short* HprojQ  = (unsigned short*)alloc((size_t)T_STEPS * BB * HH * 2);
    unsigned short* HpprojQ = (unsigned short*)alloc((size_t)T_STEPS * BB * HH * 2);
    unsigned short* PprojQ  = (unsigned short*)alloc((size_t)T_STEPS * BB * HH * 2);
    float*          DiffQ   = (float*)alloc((size_t)T_STEPS * BB * ZZ * 4);
    float*          MtQ     = (float*)alloc((size_t)T_STEPS * BB * 4);
    unsigned short* W1z_p   = (unsigned short*)alloc((size_t)ZZ * HH * 2);
    unsigned short* W2_p    = (unsigned short*)alloc((size_t)HH * ZZ * 2);
    unsigned short* PW1z_p  = (unsigned short*)alloc((size_t)ZZ * HH * 2);
    unsigned short* PW2_p   = (unsigned short*)alloc((size_t)HH * DD * 2);
    unsigned short* W1h_p   = (unsigned short*)alloc((size_t)RR * HH * 2);
    unsigned short* PW1h_p  = (unsigned short*)alloc((size_t)RR * HH * 2);
    unsigned short* DW1_p   = (unsigned short*)alloc((size_t)RR * HH * 2);
    unsigned short* DW2_p   = (unsigned short*)alloc((size_t)HH * ZZ * 2);

    hipMemsetAsync(d_out, 0, (size_t)out_size * sizeof(float), stream);

    auto packLaunch = [&](const float* src, int K, int N, unsigned short* dst) {
        int total = (K / 32) * (N / 16) * 64;
        pack_w<<<(total + 255) / 256, 256, 0, stream>>>(src, K, N, dst);
    };
    // scan weights (z-parts / second layers)
    packLaunch(drift_w1 + (size_t)RR * HH, ZZ, HH, W1z_p);   // drift_w1[R:, :]
    packLaunch(drift_w2,                   HH, ZZ, W2_p);
    packLaunch(p_w1 + (size_t)RR * HH,     ZZ, HH, PW1z_p);  // p_w1[R:, :]
    packLaunch(p_w2,                       HH, DD, PW2_p);
    // precompute weights (h-parts + diffusion)
    packLaunch(drift_w1, RR, HH, W1h_p);
    packLaunch(p_w1,     RR, HH, PW1h_p);
    packLaunch(diff_w1,  RR, HH, DW1_p);
    packLaunch(diff_w2,  HH, ZZ, DW2_p);

    mt_kernel<<<(T_STEPS * BB * 64) / 256, 256, 0, stream>>>(M, MtQ);

    precompute_kernel<<<(T_STEPS * BB) / 16, 256, 0, stream>>>(
        path_h, path_hpos, drift_b1, p_b1, diff_b1, diff_b2,
        W1h_p, PW1h_p, DW1_p, DW2_p, HprojQ, HpprojQ, PprojQ, DiffQ);

    scan_kernel<<<BB, 1024, 0, stream>>>(
        X, cov, noise, drift_b2, p_b2, cov_w1, cov_b1, cov_w2, cov_b2,
        W1z_p, W2_p, PW1z_p, PW2_p, HprojQ, HpprojQ, PprojQ, DiffQ, MtQ,
        (float*)d_out);
}

// Round 2
// 5592.485 us; speedup vs baseline: 2.2010x; 2.2010x over previous
//
#include <hip/hip_runtime.h>
#include <cstddef>
#include <cstdint>

#define T_STEPS 200
#define BB 64
#define SS 8
#define DD 128
#define RR 512
#define ZZ 256
#define HH 1024
#define DT 0.05f
#define SQRT_DT 0.22360679774997896f
#define LOG2PIF 1.8378770664093453f

typedef __attribute__((ext_vector_type(8))) short bf16x8;
typedef __attribute__((ext_vector_type(4))) float f32x4;
#define MFMA __builtin_amdgcn_mfma_f32_16x16x32_bf16

static __device__ __forceinline__ unsigned short f2bf(float x) {
    unsigned int u = __builtin_bit_cast(unsigned int, x);
    u += 0x7fffu + ((u >> 16) & 1u);
    return (unsigned short)(u >> 16);
}
static __device__ __forceinline__ float bf2f(unsigned short h) {
    unsigned int u = ((unsigned int)h) << 16;
    return __builtin_bit_cast(float, u);
}
static __device__ __forceinline__ float fast_tanh(float x) {
    float e = __expf(2.0f * x);
    return 1.0f - 2.0f / (e + 1.0f);
}

// ---------------------------------------------------------------------------
// Pack row-major fp32 W[K][N] into bf16 MFMA B-fragment order:
// frag p = nt*(K/32)*64 + ks*64 + lane holds 8 elems: n = nt*16 + (lane&15),
// k = ks*32 + (lane>>4)*8 + i.
// ---------------------------------------------------------------------------
__global__ void pack_w(const float* __restrict__ src, int K, int N,
                       unsigned short* __restrict__ dst) {
    int total = (K >> 5) * (N >> 4) * 64;
    int p = blockIdx.x * blockDim.x + threadIdx.x;
    if (p >= total) return;
    int lane = p & 63;
    int ksteps = K >> 5;
    int ks = (p >> 6) % ksteps;
    int nt = p / (ksteps << 6);
    int n = (nt << 4) + (lane & 15);
    int k0 = (ks << 5) + ((lane >> 4) << 3);
    uint4 u4;
    unsigned short* tmp = reinterpret_cast<unsigned short*>(&u4);
    for (int i = 0; i < 8; ++i) tmp[i] = f2bf(src[(size_t)(k0 + i) * N + n]);
    *reinterpret_cast<uint4*>(dst + (size_t)p * 8) = u4;
}

// Mt[t,b] = mean over D of M[t,b,:]
__global__ void mt_kernel(const float* __restrict__ M, float* __restrict__ Mt) {
    int wv = (blockIdx.x * blockDim.x + threadIdx.x) >> 6;
    int lane = threadIdx.x & 63;
    if (wv >= T_STEPS * BB) return;
    const float* row = M + (size_t)wv * DD;
    float s = row[lane] + row[lane + 64];
    for (int off = 32; off; off >>= 1) s += __shfl_down(s, off, 64);
    if (lane == 0) Mt[wv] = s * (1.0f / DD);
}

// ---------------------------------------------------------------------------
// Precompute h-only projections (parallel over T*B, 16 rows/block).
// ---------------------------------------------------------------------------
#define PC_GEMM_1024(Asrc, Bp, biasArr, EMIT)                                    \
    {                                                                            \
        f32x4 acc[16];                                                           \
        f32x4 z4 = {0.f, 0.f, 0.f, 0.f};                                        \
        for (int ntl = 0; ntl < 16; ++ntl) acc[ntl] = z4;                        \
        for (int ks = 0; ks < 16; ++ks) {                                        \
            bf16x8 a = *(const bf16x8*)&Asrc[l][(ks << 5) + (q << 3)];           \
            for (int ntl = 0; ntl < 16; ++ntl) {                                 \
                int ntg = (w << 4) + ntl;                                        \
                bf16x8 bb = *(const bf16x8*)(Bp +                                \
                             (((size_t)ntg * 16 + ks) * 64 + lane) * 8);         \
                acc[ntl] = MFMA(a, bb, acc[ntl], 0, 0, 0);                       \
            }                                                                    \
        }                                                                        \
        for (int ntl = 0; ntl < 16; ++ntl) {                                     \
            int n = (((w << 4) + ntl) << 4) + l;                                 \
            float bv = biasArr[n];                                               \
            for (int i = 0; i < 4; ++i) {                                        \
                int rr = (q << 2) + i;                                           \
                float v = acc[ntl][i] + bv;                                      \
                EMIT;                                                            \
            }                                                                    \
        }                                                                        \
    }

__global__ __launch_bounds__(256)
void precompute_kernel(const float* __restrict__ h, const float* __restrict__ hpos,
                       const float* __restrict__ b1d, const float* __restrict__ b1p,
                       const float* __restrict__ b1f, const float* __restrict__ b2f,
                       const unsigned short* __restrict__ W1h_p,
                       const unsigned short* __restrict__ PW1h_p,
                       const unsigned short* __restrict__ DW1_p,
                       const unsigned short* __restrict__ DW2_p,
                       unsigned short* __restrict__ HprojQ,
                       unsigned short* __restrict__ HpprojQ,
                       unsigned short* __restrict__ PprojQ,
                       float* __restrict__ DiffQ) {
    __shared__ unsigned short Ahh[16][RR + 8];
    __shared__ unsigned short Ahp[16][RR + 8];
    __shared__ unsigned short Adh[16][HH + 8];
    const int tid = threadIdx.x;
    const int lane = tid & 63;
    const int w = tid >> 6;
    const int q = lane >> 4;
    const int l = lane & 15;
    const int r0 = blockIdx.x << 4;

    for (int idx = tid; idx < (RR << 4); idx += 256) {
        int r = idx >> 9, c = idx & (RR - 1);
        Ahh[r][c] = f2bf(h[(size_t)(r0 + r) * RR + c]);
        Ahp[r][c] = f2bf(hpos[(size_t)(r0 + r) * RR + c]);
    }
    __syncthreads();

    PC_GEMM_1024(Ahh, W1h_p,  b1d, (HprojQ [(size_t)(r0 + rr) * HH + n] = f2bf(v)));
    PC_GEMM_1024(Ahp, W1h_p,  b1d, (HpprojQ[(size_t)(r0 + rr) * HH + n] = f2bf(v)));
    PC_GEMM_1024(Ahh, PW1h_p, b1p, (PprojQ [(size_t)(r0 + rr) * HH + n] = f2bf(v)));
    PC_GEMM_1024(Ahh, DW1_p,  b1f, (Adh[rr][n] = f2bf(fmaxf(v, 0.f))));
    __syncthreads();

    {
        f32x4 acc[4];
        f32x4 z4 = {0.f, 0.f, 0.f, 0.f};
        for (int ntl = 0; ntl < 4; ++ntl) acc[ntl] = z4;
        for (int ks = 0; ks < 32; ++ks) {
            bf16x8 a = *(const bf16x8*)&Adh[l][(ks << 5) + (q << 3)];
            for (int ntl = 0; ntl < 4; ++ntl) {
                int ntg = (w << 2) + ntl;
                bf16x8 bb = *(const bf16x8*)(DW2_p +
                             (((size_t)ntg * 32 + ks) * 64 + lane) * 8);
                acc[ntl] = MFMA(a, bb, acc[ntl], 0, 0, 0);
            }
        }
        for (int ntl = 0; ntl < 4; ++ntl) {
            int n = (((w << 2) + ntl) << 4) + l;
            float bv = b2f[n];
            for (int i = 0; i < 4; ++i) {
                int rr = (q << 2) + i;
                DiffQ[(size_t)(r0 + rr) * ZZ + n] = __expf(acc[ntl][i] + bv);
            }
        }
    }
}

// ---------------------------------------------------------------------------
// Sequential scan, POSTERIOR PATH ONLY. 64 blocks x 1024 thr (16 waves).
// Per step: G1 (z@W1z -> relu) , G2 (hidden@W2 -> z update), normalize.
// Weight fragments streamed with depth-8 circular register prefetch.
// z history logged (bf16) for the parallel post kernels.
// ---------------------------------------------------------------------------
__global__ __launch_bounds__(1024)
void scan_kernel(const float* __restrict__ cov, const float* __restrict__ noise,
                 const float* __restrict__ b2d,
                 const float* __restrict__ cw1, const float* __restrict__ cb1,
                 const float* __restrict__ cw2, const float* __restrict__ cb2,
                 const unsigned short* __restrict__ W1z_p,
                 const unsigned short* __restrict__ W2_p,
                 const unsigned short* __restrict__ HpprojQ,
                 const float* __restrict__ DiffQ,
                 unsigned short* __restrict__ zhist,
                 float* __restrict__ out) {
    __shared__ unsigned short Az[16][ZZ + 8];   // z bf16; rows 8..15 stay 0
    __shared__ unsigned short Ah[16][HH + 8];   // poster hidden; rows 8..15 stay 0
    __shared__ float zf[SS][ZZ];                // fp32 master state
    __shared__ unsigned short Hpp_t[HH];
    __shared__ float Diff_t[ZZ];
    __shared__ float b2d_s[ZZ];
    __shared__ float ch[64];

    const int tid = threadIdx.x;
    const int lane = tid & 63;
    const int w = tid >> 6;   // 16 waves
    const int q = lane >> 4;
    const int l = lane & 15;
    const int b = blockIdx.x;

    for (int idx = tid; idx < 16 * (ZZ + 8); idx += 1024) ((unsigned short*)Az)[idx] = 0;
    for (int idx = tid; idx < 16 * (HH + 8); idx += 1024) ((unsigned short*)Ah)[idx] = 0;
    if (tid < ZZ) b2d_s[tid] = b2d[tid];
    if (tid < 64) {
        float s = cb1[tid];
        for (int c = 0; c < 16; ++c) s += cov[b * 16 + c] * cw1[c * 64 + tid];
        ch[tid] = fmaxf(s, 0.f);
    }
    __syncthreads();
    if (tid < ZZ) {
        float v = cb2[tid];
        for (int j = 0; j < 64; ++j) v += ch[j] * cw2[j * ZZ + tid];
        v = fast_tanh(v);
        unsigned short hv = f2bf(v);
        for (int s = 0; s < SS; ++s) {
            zf[s][tid] = v;
            Az[s][tid] = hv;
            zhist[((size_t)b * SS + s) * ZZ + tid] = hv;   // slot 0
        }
    }
    // initial staging for t=0
    if (tid < 512) {
        *(ushort2*)&Hpp_t[tid * 2] = *(const ushort2*)&HpprojQ[(size_t)b * HH + tid * 2];
    } else if (tid < 768) {
        int i2 = tid - 512;
        Diff_t[i2] = DiffQ[(size_t)b * ZZ + i2];
    }

    for (int t = 0; t < T_STEPS; ++t) {
        const size_t tb = (size_t)t * BB + b;

        // --- preloads issued BEFORE the barrier (addresses step-independent) ---
        float eps[4];
        if (q < 2) {
            #pragma unroll
            for (int i = 0; i < 4; ++i)
                eps[i] = noise[((tb << 3) + (q << 2) + i) * ZZ + (w << 4) + l];
        }
        const unsigned short* wb1 = W1z_p + lane * 8;
        bf16x8 wq1[8];
        #pragma unroll
        for (int f = 0; f < 8; ++f) {
            int ks = f >> 2, ntl = f & 3;
            wq1[f] = *(const bf16x8*)(wb1 + ((size_t)(((w << 2) + ntl) * 8 + ks)) * 512);
        }
        __syncthreads();   // Az + staging ready

        // ---- G1: hidden = relu(Hpp + z @ W1z)
        f32x4 acc[4];
        {
            f32x4 z4 = {0.f, 0.f, 0.f, 0.f};
            #pragma unroll
            for (int ntl = 0; ntl < 4; ++ntl) acc[ntl] = z4;
        }
        #pragma unroll
        for (int f = 0; f < 32; ++f) {
            int ks = f >> 2, ntl = f & 3;
            bf16x8 a = *(const bf16x8*)&Az[l][(ks << 5) + (q << 3)];
            acc[ntl] = MFMA(a, wq1[f & 7], acc[ntl], 0, 0, 0);
            if (f < 24) {
                int f2 = f + 8, ks2 = f2 >> 2, ntl2 = f2 & 3;
                wq1[f & 7] = *(const bf16x8*)(wb1 + ((size_t)(((w << 2) + ntl2) * 8 + ks2)) * 512);
            }
        }
        // preload G2 fragments while emitting (keeps VMEM queue busy across barrier)
        const unsigned short* wb2 = W2_p + (size_t)w * 32 * 512 + lane * 8;
        bf16x8 wq2[8];
        #pragma unroll
        for (int f = 0; f < 8; ++f) wq2[f] = *(const bf16x8*)(wb2 + (size_t)f * 512);

        if (q < 2) {
            #pragma unroll
            for (int ntl = 0; ntl < 4; ++ntl) {
                int n = (((w << 2) + ntl) << 4) + l;
                float base = bf2f(Hpp_t[n]);
                #pragma unroll
                for (int i = 0; i < 4; ++i)
                    Ah[(q << 2) + i][n] = f2bf(fmaxf(base + acc[ntl][i], 0.f));
            }
        }
        __syncthreads();

        // ---- G2: drift_pre = hidden @ W2 ; z update
        f32x4 acc2a = {0.f, 0.f, 0.f, 0.f};
        f32x4 acc2b = {0.f, 0.f, 0.f, 0.f};
        #pragma unroll
        for (int f = 0; f < 32; ++f) {
            bf16x8 a = *(const bf16x8*)&Ah[l][(f << 5) + (q << 3)];
            if (f & 1) acc2b = MFMA(a, wq2[f & 7], acc2b, 0, 0, 0);
            else       acc2a = MFMA(a, wq2[f & 7], acc2a, 0, 0, 0);
            if (f < 24) wq2[f & 7] = *(const bf16x8*)(wb2 + (size_t)(f + 8) * 512);
        }
        if (q < 2) {
            int n = (w << 4) + l;
            float bias = b2d_s[n], dif = Diff_t[n];
            #pragma unroll
            for (int i = 0; i < 4; ++i) {
                int s = (q << 2) + i;
                float pre = acc2a[i] + acc2b[i] + bias;
                float po = 0.1f * fast_tanh(pre);
                zf[s][n] += DT * po + SQRT_DT * dif * eps[i];
            }
        }
        __syncthreads();

        // ---- normalize (waves 0-7) | stage next step (waves 8-15)
        if (w < SS) {
            float v0 = zf[w][lane], v1 = zf[w][lane + 64];
            float v2 = zf[w][lane + 128], v3 = zf[w][lane + 192];
            float mn = fminf(fminf(v0, v1), fminf(v2, v3));
            float mx = fmaxf(fmaxf(v0, v1), fmaxf(v2, v3));
            for (int off = 32; off; off >>= 1) {
                mn = fminf(mn, __shfl_xor(mn, off, 64));
                mx = fmaxf(mx, __shfl_xor(mx, off, 64));
            }
            float sc = 1.0f / (mx - mn);
            v0 = (v0 - mn) * sc; v1 = (v1 - mn) * sc;
            v2 = (v2 - mn) * sc; v3 = (v3 - mn) * sc;
            zf[w][lane] = v0; zf[w][lane + 64] = v1;
            zf[w][lane + 128] = v2; zf[w][lane + 192] = v3;
            unsigned short h0 = f2bf(v0), h1 = f2bf(v1), h2 = f2bf(v2), h3 = f2bf(v3);
            Az[w][lane] = h0; Az[w][lane + 64] = h1;
            Az[w][lane + 128] = h2; Az[w][lane + 192] = h3;
            size_t zo = ((size_t)(t + 1) * BB + b) * (SS * ZZ) + (size_t)w * ZZ;
            zhist[zo + lane] = h0; zhist[zo + lane + 64] = h1;
            zhist[zo + lane + 128] = h2; zhist[zo + lane + 192] = h3;
        } else if (t < T_STEPS - 1) {
            size_t tb1 = tb + BB;
            int idx = tid - 512;
            *(ushort2*)&Hpp_t[idx * 2] = *(const ushort2*)&HpprojQ[tb1 * HH + idx * 2];
            if (idx < ZZ) Diff_t[idx] = DiffQ[tb1 * ZZ + idx];
        }
    }
    __syncthreads();

    for (int idx = tid; idx < SS * ZZ; idx += 1024) {
        int s = idx >> 8, n = idx & 255;
        out[((size_t)b * SS + s) * ZZ + n] = zf[s][n];
    }
}

// ---------------------------------------------------------------------------
// Parallel post-pass 1: prior+poster drift recompute -> kld.
// 1600 blocks x 512 thr; 8 (t,b) pairs = 64 A-rows per block; K-chunked.
// ---------------------------------------------------------------------------
__global__ __launch_bounds__(512, 4)
void post_drift(const unsigned short* __restrict__ zhist,
                const unsigned short* __restrict__ HprojQ,
                const unsigned short* __restrict__ HpprojQ,
                const float* __restrict__ DiffQ, const float* __restrict__ b2d,
                const unsigned short* __restrict__ W1z_p,
                const unsigned short* __restrict__ W2_p,
                float* __restrict__ loss) {
    __shared__ unsigned short Az[4][16][ZZ + 8];
    __shared__ unsigned short Hp[2][4][16][136];
    __shared__ unsigned short ProjS[2][8][128];
    __shared__ float b2d_s[ZZ];
    __shared__ float red[8];
    const int tid = threadIdx.x;
    const int lane = tid & 63;
    const int w = tid >> 6;      // 8 waves
    const int q = lane >> 4;
    const int l = lane & 15;
    const int rt = w & 3;
    const int half = w >> 2;
    const int p0 = blockIdx.x << 3;   // first flat (t*B+b) pair

    for (int idx = tid; idx < 4096; idx += 512) {
        int r = idx >> 6, c4 = (idx & 63) << 2;
        *(ushort4*)&Az[r >> 4][r & 15][c4] =
            *(const ushort4*)&zhist[((size_t)p0 * SS + r) * ZZ + c4];
    }
    if (tid < ZZ) b2d_s[tid] = b2d[tid];

    f32x4 accP[8], accQ[8];
    {
        f32x4 z4 = {0.f, 0.f, 0.f, 0.f};
        #pragma unroll
        for (int j = 0; j < 8; ++j) { accP[j] = z4; accQ[j] = z4; }
    }

    for (int nc = 0; nc < 8; ++nc) {
        {   // stage Hproj/Hpproj slices for this chunk
            int path = tid >> 8, rem = tid & 255;
            int pair = rem >> 5, c4 = (rem & 31) << 2;
            const unsigned short* src =
                (path ? HpprojQ : HprojQ) + (size_t)(p0 + pair) * HH + nc * 128 + c4;
            *(ushort4*)&ProjS[path][pair][c4] = *(const ushort4*)src;
        }
        __syncthreads();   // ProjS ready; prev G2's Hp reads done

        // zW1 chunk [64 x 128]
        f32x4 za[4];
        {
            f32x4 z4 = {0.f, 0.f, 0.f, 0.f};
            #pragma unroll
            for (int j = 0; j < 4; ++j) za[j] = z4;
        }
        {
            const unsigned short* wb = W1z_p + lane * 8;
            bf16x8 wq[4];
            #pragma unroll
            for (int f = 0; f < 4; ++f) {
                int ks = f >> 2, j = f & 3;
                wq[f] = *(const bf16x8*)(wb +
                    ((size_t)((nc * 8 + half * 4 + j) * 8 + ks)) * 512);
            }
            #pragma unroll
            for (int f = 0; f < 32; ++f) {
                int ks = f >> 2, j = f & 3;
                bf16x8 a = *(const bf16x8*)&Az[rt][l][(ks << 5) + (q << 3)];
                za[j] = MFMA(a, wq[f & 3], za[j], 0, 0, 0);
                if (f < 28) {
                    int f2 = f + 4, ks2 = f2 >> 2, j2 = f2 & 3;
                    wq[f & 3] = *(const bf16x8*)(wb +
                        ((size_t)((nc * 8 + half * 4 + j2) * 8 + ks2)) * 512);
                }
            }
        }
        #pragma unroll
        for (int j = 0; j < 4; ++j) {
            int c = (half * 4 + j) * 16 + l;
            #pragma unroll
            for (int i = 0; i < 4; ++i) {
                int r = (q << 2) + i;
                int pair = ((rt << 4) + r) >> 3;
                float v = za[j][i];
                Hp[0][rt][r][c] = f2bf(fmaxf(bf2f(ProjS[0][pair][c]) + v, 0.f));
                Hp[1][rt][r][c] = f2bf(fmaxf(bf2f(ProjS[1][pair][c]) + v, 0.f));
            }
        }
        __syncthreads();

        // G2 chunk: acc += hp @ W2[nc-chunk]
        {
            const unsigned short* wb2 = W2_p + lane * 8;
            bf16x8 wq2[4];
            #pragma unroll
            for (int f = 0; f < 4; ++f) {
                int kk = f >> 3, j = f & 7;
                wq2[f] = *(const bf16x8*)(wb2 +
                    ((size_t)((half * 8 + j) * 32 + nc * 4 + kk)) * 512);
            }
            #pragma unroll
            for (int f = 0; f < 32; ++f) {
                int kk = f >> 3, j = f & 7;
                bf16x8 aP = *(const bf16x8*)&Hp[0][rt][l][(kk << 5) + (q << 3)];
                bf16x8 aQ = *(const bf16x8*)&Hp[1][rt][l][(kk << 5) + (q << 3)];
                accP[j] = MFMA(aP, wq2[f & 3], accP[j], 0, 0, 0);
                accQ[j] = MFMA(aQ, wq2[f & 3], accQ[j], 0, 0, 0);
                if (f < 28) {
                    int f2 = f + 4, kk2 = f2 >> 3, j2 = f2 & 7;
                    wq2[f & 3] = *(const bf16x8*)(wb2 +
                        ((size_t)((half * 8 + j2) * 32 + nc * 4 + kk2)) * 512);
                }
            }
        }
        __syncthreads();
    }

    float kld_local = 0.f;
    #pragma unroll
    for (int j = 0; j < 8; ++j) {
        int n = ((half << 3) + j) * 16 + l;
        float bias = b2d_s[n];
        #pragma unroll
        for (int i = 0; i < 4; ++i) {
            int r = (rt << 4) + (q << 2) + i;
            int pair = p0 + (r >> 3);
            float pr = 0.1f * fast_tanh(accP[j][i] + bias);
            float po = 0.1f * fast_tanh(accQ[j][i] + bias);
            float e = (pr - po) / DiffQ[(size_t)pair * ZZ + n];
            kld_local += e * e;
        }
    }
    for (int off = 32; off; off >>= 1) kld_local += __shfl_down(kld_local, off, 64);
    if (lane == 0) red[w] = kld_local;
    __syncthreads();
    if (tid == 0) {
        float K = 0.f;
        for (int i = 0; i < 8; ++i) K += red[i];
        float kc = K * (0.5f * DT / (SS * BB));
        atomicAdd(loss + 0, kc);
        atomicAdd(loss + 2, kc);
    }
}

// ---------------------------------------------------------------------------
// Parallel post-pass 2: decoder on z_{t+1} -> recon.
// ---------------------------------------------------------------------------
__global__ __launch_bounds__(512, 4)
void post_dec(const unsigned short* __restrict__ zhist,
              const unsigned short* __restrict__ PprojQ,
              const float* __restrict__ X, const float* __restrict__ MtQ,
              const float* __restrict__ b2p,
              const unsigned short* __restrict__ PW1z_p,
              const unsigned short* __restrict__ PW2_p,
              float* __restrict__ loss) {
    __shared__ unsigned short Az[4][16][ZZ + 8];
    __shared__ unsigned short Hp[4][16][136];
    __shared__ unsigned short ProjS[8][128];
    __shared__ float b2p_s[DD];
    __shared__ float red[8];
    const int tid = threadIdx.x;
    const int lane = tid & 63;
    const int w = tid >> 6;
    const int q = lane >> 4;
    const int l = lane & 15;
    const int rt = w & 3;
    const int half = w >> 2;
    const int p0 = blockIdx.x << 3;

    for (int idx = tid; idx < 4096; idx += 512) {
        int r = idx >> 6, c4 = (idx & 63) << 2;
        *(ushort4*)&Az[r >> 4][r & 15][c4] =
            *(const ushort4*)&zhist[((size_t)(p0 + BB) * SS + r) * ZZ + c4];  // slot t+1
    }
    if (tid < DD) b2p_s[tid] = b2p[tid];

    f32x4 pacc[4];
    {
        f32x4 z4 = {0.f, 0.f, 0.f, 0.f};
        #pragma unroll
        for (int j = 0; j < 4; ++j) pacc[j] = z4;
    }

    for (int nc = 0; nc < 8; ++nc) {
        if (tid < 256) {
            int pair = tid >> 5, c4 = (tid & 31) << 2;
            *(ushort4*)&ProjS[pair][c4] =
                *(const ushort4*)&PprojQ[(size_t)(p0 + pair) * HH + nc * 128 + c4];
        }
        __syncthreads();

        f32x4 za[4];
        {
            f32x4 z4 = {0.f, 0.f, 0.f, 0.f};
            #pragma unroll
            for (int j = 0; j < 4; ++j) za[j] = z4;
        }
        {
            const unsigned short* wb = PW1z_p + lane * 8;
            bf16x8 wq[4];
            #pragma unroll
            for (int f = 0; f < 4; ++f) {
                int ks = f >> 2, j = f & 3;
                wq[f] = *(const bf16x8*)(wb +
                    ((size_t)((nc * 8 + half * 4 + j) * 8 + ks)) * 512);
            }
            #pragma unroll
            for (int f = 0; f < 32; ++f) {
                int ks = f >> 2, j = f & 3;
                bf16x8 a = *(const bf16x8*)&Az[rt][l][(ks << 5) + (q << 3)];
                za[j] = MFMA(a, wq[f & 3], za[j], 0, 0, 0);
                if (f < 28) {
                    int f2 = f + 4, ks2 = f2 >> 2, j2 = f2 & 3;
                    wq[f & 3] = *(const bf16x8*)(wb +
                        ((size_t)((nc * 8 + half * 4 + j2) * 8 + ks2)) * 512);
                }
            }
        }
        #pragma unroll
        for (int j = 0; j < 4; ++j) {
            int c = (half * 4 + j) * 16 + l;
            #pragma unroll
            for (int i = 0; i < 4; ++i) {
                int r = (q << 2) + i;
                int pair = ((rt << 4) + r) >> 3;
                Hp[rt][r][c] = f2bf(fmaxf(bf2f(ProjS[pair][c]) + za[j][i], 0.f));
            }
        }
        __syncthreads();

        {   // pacc += hp @ PW2[nc-chunk]   (N=128 -> 8 ntiles)
            const unsigned short* wb2 = PW2_p + lane * 8;
            bf16x8 wq2[4];
            #pragma unroll
            for (int f = 0; f < 4; ++f) {
                int kk = f >> 2, j = f & 3;
                wq2[f] = *(const bf16x8*)(wb2 +
                    ((size_t)((half * 4 + j) * 32 + nc * 4 + kk)) * 512);
            }
            #pragma unroll
            for (int f = 0; f < 16; ++f) {
                int kk = f >> 2, j = f & 3;
                bf16x8 a = *(const bf16x8*)&Hp[rt][l][(kk << 5) + (q << 3)];
                pacc[j] = MFMA(a, wq2[f & 3], pacc[j], 0, 0, 0);
                if (f < 12) {
                    int f2 = f + 4, kk2 = f2 >> 2, j2 = f2 & 3;
                    wq2[f & 3] = *(const bf16x8*)(wb2 +
                        ((size_t)((half * 4 + j2) * 32 + nc * 4 + kk2)) * 512);
                }
            }
        }
        __syncthreads();
    }

    float rl = 0.f;
    #pragma unroll
    for (int j = 0; j < 4; ++j) {
        int n = ((half << 2) + j) * 16 + l;
        float bias = b2p_s[n];
        #pragma unroll
        for (int i = 0; i < 4; ++i) {
            int r = (rt << 4) + (q << 2) + i;
            int pair = p0 + (r >> 3);
            float p = pacc[j][i] + bias;
            float d = X[(size_t)pair * DD + n] - p;
            rl += (0.5f * (LOG2PIF + d * d)) * MtQ[pair];
        }
    }
    rl *= 1.0f / (SS * BB);
    for (int off = 32; off; off >>= 1) rl += __shfl_down(rl, off, 64);
    if (lane == 0) red[w] = rl;
    __syncthreads();
    if (tid == 0) {
        float R = 0.f;
        for (int i = 0; i < 8; ++i) R += red[i];
        atomicAdd(loss + 0, R);
        atomicAdd(loss + 1, R);
    }
}

extern "C" void kernel_launch(void* const* d_in, const int* in_sizes, int n_in,
                              void* d_out, int out_size, void* d_ws, size_t ws_size,
                              hipStream_t stream) {
    (void)in_sizes; (void)n_in; (void)ws_size;
    const float* X         = (const float*)d_in[0];
    const float* M         = (const float*)d_in[1];
    const float* cov       = (const float*)d_in[2];
    const float* path_h    = (const float*)d_in[3];
    const float* path_hpos = (const float*)d_in[4];
    const float* noise     = (const float*)d_in[5];
    const float* drift_w1  = (const float*)d_in[6];
    const float* drift_b1  = (const float*)d_in[7];
    const float* drift_w2  = (const float*)d_in[8];
    const float* drift_b2  = (const float*)d_in[9];
    const float* diff_w1   = (const float*)d_in[10];
    const float* diff_b1   = (const float*)d_in[11];
    const float* diff_w2   = (const float*)d_in[12];
    const float* diff_b2   = (const float*)d_in[13];
    const float* p_w1      = (const float*)d_in[14];
    const float* p_b1      = (const float*)d_in[15];
    const float* p_w2      = (const float*)d_in[16];
    const float* p_b2      = (const float*)d_in[17];
    const float* cov_w1    = (const float*)d_in[18];
    const float* cov_b1    = (const float*)d_in[19];
    const float* cov_w2    = (const float*)d_in[20];
    const float* cov_b2    = (const float*)d_in[21];

    char* ws = (char*)d_ws;
    size_t off = 0;
    auto alloc = [&](size_t bytes) {
        void* p = ws + off;
        off = (off + bytes + 255) & ~(size_t)255;
        return p;
    };
    unsigned short* HprojQ  = (unsigned short*)alloc((size_t)T_STEPS * BB * HH * 2);
    unsigned short* HpprojQ = (unsigned short*)alloc((size_t)T_STEPS * BB * HH * 2);
    unsigned short* PprojQ  = (unsigned short*)alloc((size_t)T_STEPS * BB * HH * 2);
    float*          DiffQ   = (float*)alloc((size_t)T_STEPS * BB * ZZ * 4);
    float*          MtQ     = (float*)alloc((size_t)T_STEPS * BB * 4);
    unsigned short* zhist   = (unsigned short*)alloc((size_t)(T_STEPS + 1) * BB * SS * ZZ * 2);
    unsigned short* W1z_p   = (unsigned short*)alloc((size_t)ZZ * HH * 2);
    unsigned short* W2_p    = (unsigned short*)alloc((size_t)HH * ZZ * 2);
    unsigned short* PW1z_p  = (unsigned short*)alloc((size_t)ZZ * HH * 2);
    unsigned short* PW2_p   = (unsigned short*)alloc((size_t)HH * DD * 2);
    unsigned short* W1h_p   = (unsigned short*)alloc((size_t)RR * HH * 2);
    unsigned short* PW1h_p  = (unsigned short*)alloc((size_t)RR * HH * 2);
    unsigned short* DW1_p   = (unsigned short*)alloc((size_t)RR * HH * 2);
    unsigned short* DW2_p   = (unsigned short*)alloc((size_t)HH * ZZ * 2);

    hipMemsetAsync(d_out, 0, (size_t)out_size * sizeof(float), stream);

    auto packLaunch = [&](const float* src, int K, int N, unsigned short* dst) {
        int total = (K / 32) * (N / 16) * 64;
        pack_w<<<(total + 255) / 256, 256, 0, stream>>>(src, K, N, dst);
    };
    packLaunch(drift_w1 + (size_t)RR * HH, ZZ, HH, W1z_p);
    packLaunch(drift_w2,                   HH, ZZ, W2_p);
    packLaunch(p_w1 + (size_t)RR * HH,     ZZ, HH, PW1z_p);
    packLaunch(p_w2,                       HH, DD, PW2_p);
    packLaunch(drift_w1, RR, HH, W1h_p);
    packLaunch(p_w1,     RR, HH, PW1h_p);
    packLaunch(diff_w1,  RR, HH, DW1_p);
    packLaunch(diff_w2,  HH, ZZ, DW2_p);

    mt_kernel<<<(T_STEPS * BB * 64) / 256, 256, 0, stream>>>(M, MtQ);

    precompute_kernel<<<(T_STEPS * BB) / 16, 256, 0, stream>>>(
        path_h, path_hpos, drift_b1, p_b1, diff_b1, diff_b2,
        W1h_p, PW1h_p, DW1_p, DW2_p, HprojQ, HpprojQ, PprojQ, DiffQ);

    float* outp = (float*)d_out;
    float* loss = outp + (size_t)BB * SS * ZZ;

    scan_kernel<<<BB, 1024, 0, stream>>>(
        cov, noise, drift_b2, cov_w1, cov_b1, cov_w2, cov_b2,
        W1z_p, W2_p, HpprojQ, DiffQ, zhist, outp);

    post_drift<<<(T_STEPS * BB) / 8, 512, 0, stream>>>(
        zhist, HprojQ, HpprojQ, DiffQ, drift_b2, W1z_p, W2_p, loss);

    post_dec<<<(T_STEPS * BB) / 8, 512, 0, stream>>>(
        zhist, PprojQ, X, MtQ, p_b2, PW1z_p, PW2_p, loss);
}

// Round 3
// 4523.204 us; speedup vs baseline: 2.7213x; 1.2364x over previous
//
#include <hip/hip_runtime.h>
#include <cstddef>
#include <cstdint>

#define T_STEPS 200
#define BB 64
#define SS 8
#define DD 128
#define RR 512
#define ZZ 256
#define HH 1024
#define DT 0.05f
#define SQRT_DT 0.22360679774997896f
#define LOG2PIF 1.8378770664093453f

typedef __attribute__((ext_vector_type(8))) short bf16x8;
typedef __attribute__((ext_vector_type(4))) float f32x4;
#define MFMA __builtin_amdgcn_mfma_f32_16x16x32_bf16

// async global->LDS DMA, 16 B per lane (lds dst = wave-uniform base + lane*16)
#define ASYNC16(gsrc, ldst)                                                     \
    __builtin_amdgcn_global_load_lds(                                           \
        (const __attribute__((address_space(1))) unsigned int*)(gsrc),          \
        (__attribute__((address_space(3))) unsigned int*)(ldst), 16, 0, 0)

// wait until <= N vmem ops outstanding (lgkm/exp = don't care)
#define WAITVM(n) __builtin_amdgcn_s_waitcnt(((n) & 15) | (((n) >> 4) << 14) | 0x70 | 0xF00)

static __device__ __forceinline__ unsigned short f2bf(float x) {
    unsigned int u = __builtin_bit_cast(unsigned int, x);
    u += 0x7fffu + ((u >> 16) & 1u);
    return (unsigned short)(u >> 16);
}
static __device__ __forceinline__ float bf2f(unsigned short h) {
    unsigned int u = ((unsigned int)h) << 16;
    return __builtin_bit_cast(float, u);
}
static __device__ __forceinline__ float fast_tanh(float x) {
    float e = __expf(2.0f * x);
    return 1.0f - 2.0f / (e + 1.0f);
}

// ---------------------------------------------------------------------------
// Pack row-major fp32 W[K][N] into bf16 MFMA B-fragment order:
// frag p = nt*(K/32)*64 + ks*64 + lane holds 8 elems: n = nt*16 + (lane&15),
// k = ks*32 + (lane>>4)*8 + i.
// ---------------------------------------------------------------------------
__global__ void pack_w(const float* __restrict__ src, int K, int N,
                       unsigned short* __restrict__ dst) {
    int total = (K >> 5) * (N >> 4) * 64;
    int p = blockIdx.x * blockDim.x + threadIdx.x;
    if (p >= total) return;
    int lane = p & 63;
    int ksteps = K >> 5;
    int ks = (p >> 6) % ksteps;
    int nt = p / (ksteps << 6);
    int n = (nt << 4) + (lane & 15);
    int k0 = (ks << 5) + ((lane >> 4) << 3);
    uint4 u4;
    unsigned short* tmp = reinterpret_cast<unsigned short*>(&u4);
    for (int i = 0; i < 8; ++i) tmp[i] = f2bf(src[(size_t)(k0 + i) * N + n]);
    *reinterpret_cast<uint4*>(dst + (size_t)p * 8) = u4;
}

// Mt[t,b] = mean over D of M[t,b,:]
__global__ void mt_kernel(const float* __restrict__ M, float* __restrict__ Mt) {
    int wv = (blockIdx.x * blockDim.x + threadIdx.x) >> 6;
    int lane = threadIdx.x & 63;
    if (wv >= T_STEPS * BB) return;
    const float* row = M + (size_t)wv * DD;
    float s = row[lane] + row[lane + 64];
    for (int off = 32; off; off >>= 1) s += __shfl_down(s, off, 64);
    if (lane == 0) Mt[wv] = s * (1.0f / DD);
}

// ---------------------------------------------------------------------------
// Precompute h-only projections (parallel over T*B, 16 rows/block).
// ---------------------------------------------------------------------------
#define PC_GEMM_1024(Asrc, Bp, biasArr, EMIT)                                    \
    {                                                                            \
        f32x4 acc[16];                                                           \
        f32x4 z4 = {0.f, 0.f, 0.f, 0.f};                                        \
        for (int ntl = 0; ntl < 16; ++ntl) acc[ntl] = z4;                        \
        for (int ks = 0; ks < 16; ++ks) {                                        \
            bf16x8 a = *(const bf16x8*)&Asrc[l][(ks << 5) + (q << 3)];           \
            for (int ntl = 0; ntl < 16; ++ntl) {                                 \
                int ntg = (w << 4) + ntl;                                        \
                bf16x8 bb = *(const bf16x8*)(Bp +                                \
                             (((size_t)ntg * 16 + ks) * 64 + lane) * 8);         \
                acc[ntl] = MFMA(a, bb, acc[ntl], 0, 0, 0);                       \
            }                                                                    \
        }                                                                        \
        for (int ntl = 0; ntl < 16; ++ntl) {                                     \
            int n = (((w << 4) + ntl) << 4) + l;                                 \
            float bv = biasArr[n];                                               \
            for (int i = 0; i < 4; ++i) {                                        \
                int rr = (q << 2) + i;                                           \
                float v = acc[ntl][i] + bv;                                      \
                EMIT;                                                            \
            }                                                                    \
        }                                                                        \
    }

__global__ __launch_bounds__(256)
void precompute_kernel(const float* __restrict__ h, const float* __restrict__ hpos,
                       const float* __restrict__ b1d, const float* __restrict__ b1p,
                       const float* __restrict__ b1f, const float* __restrict__ b2f,
                       const unsigned short* __restrict__ W1h_p,
                       const unsigned short* __restrict__ PW1h_p,
                       const unsigned short* __restrict__ DW1_p,
                       const unsigned short* __restrict__ DW2_p,
                       unsigned short* __restrict__ HprojQ,
                       unsigned short* __restrict__ HpprojQ,
                       unsigned short* __restrict__ PprojQ,
                       float* __restrict__ DiffQ) {
    __shared__ unsigned short Ahh[16][RR + 8];
    __shared__ unsigned short Ahp[16][RR + 8];
    __shared__ unsigned short Adh[16][HH + 8];
    const int tid = threadIdx.x;
    const int lane = tid & 63;
    const int w = tid >> 6;
    const int q = lane >> 4;
    const int l = lane & 15;
    const int r0 = blockIdx.x << 4;

    for (int idx = tid; idx < (RR << 4); idx += 256) {
        int r = idx >> 9, c = idx & (RR - 1);
        Ahh[r][c] = f2bf(h[(size_t)(r0 + r) * RR + c]);
        Ahp[r][c] = f2bf(hpos[(size_t)(r0 + r) * RR + c]);
    }
    __syncthreads();

    PC_GEMM_1024(Ahh, W1h_p,  b1d, (HprojQ [(size_t)(r0 + rr) * HH + n] = f2bf(v)));
    PC_GEMM_1024(Ahp, W1h_p,  b1d, (HpprojQ[(size_t)(r0 + rr) * HH + n] = f2bf(v)));
    PC_GEMM_1024(Ahh, PW1h_p, b1p, (PprojQ [(size_t)(r0 + rr) * HH + n] = f2bf(v)));
    PC_GEMM_1024(Ahh, DW1_p,  b1f, (Adh[rr][n] = f2bf(fmaxf(v, 0.f))));
    __syncthreads();

    {
        f32x4 acc[4];
        f32x4 z4 = {0.f, 0.f, 0.f, 0.f};
        for (int ntl = 0; ntl < 4; ++ntl) acc[ntl] = z4;
        for (int ks = 0; ks < 32; ++ks) {
            bf16x8 a = *(const bf16x8*)&Adh[l][(ks << 5) + (q << 3)];
            for (int ntl = 0; ntl < 4; ++ntl) {
                int ntg = (w << 2) + ntl;
                bf16x8 bb = *(const bf16x8*)(DW2_p +
                             (((size_t)ntg * 32 + ks) * 64 + lane) * 8);
                acc[ntl] = MFMA(a, bb, acc[ntl], 0, 0, 0);
            }
        }
        for (int ntl = 0; ntl < 4; ++ntl) {
            int n = (((w << 2) + ntl) << 4) + l;
            float bv = b2f[n];
            for (int i = 0; i < 4; ++i) {
                int rr = (q << 2) + i;
                DiffQ[(size_t)(r0 + rr) * ZZ + n] = __expf(acc[ntl][i] + bv);
            }
        }
    }
}

// ---------------------------------------------------------------------------
// Sequential scan, posterior path only. 64 blocks x 1024 thr (16 waves).
// Weight B-fragments streamed via global_load_lds into per-wave LDS rings
// (4 slots x 2 frags), fine-grained vmcnt(4), 3-slot lookahead; the stream
// wraps mod 32 slots and never stops across stages/steps.
// ---------------------------------------------------------------------------
__global__ __launch_bounds__(1024)
void scan_kernel(const float* __restrict__ cov, const float* __restrict__ noise,
                 const float* __restrict__ b2d,
                 const float* __restrict__ cw1, const float* __restrict__ cb1,
                 const float* __restrict__ cw2, const float* __restrict__ cb2,
                 const unsigned short* __restrict__ W1z_p,
                 const unsigned short* __restrict__ W2_p,
                 const unsigned short* __restrict__ HpprojQ,
                 const float* __restrict__ DiffQ,
                 unsigned short* __restrict__ zhist,
                 float* __restrict__ out) {
    __shared__ __align__(16) unsigned short stage[16][4][1024];  // 128 KB rings
    __shared__ __align__(16) unsigned short Az[8][264];          // z bf16 (8 rows)
    __shared__ __align__(16) unsigned short Ah[8][1040];         // poster hidden
    __shared__ float zf[8][256];                                 // fp32 master z
    __shared__ float ch[64];

    const int tid = threadIdx.x;
    const int lane = tid & 63;
    const int w = tid >> 6;   // 16 waves
    const int q = lane >> 4;
    const int l = lane & 15;
    const int b = blockIdx.x;

    const unsigned short* W1b = W1z_p + (size_t)w * 16384 + lane * 8;
    const unsigned short* W2b = W2_p  + (size_t)w * 16384 + lane * 8;

    // slot u in [0,32): u<16 -> G1 (ks=u>>1, ntl pair u&1); u>=16 -> G2 (kk=2(u-16))
    auto issue = [&](int u) {
        const unsigned short *g0, *g1;
        if (u < 16) {
            g0 = W1b + ((u & 1) ? 8192 : 0) + (u >> 1) * 512;
            g1 = g0 + 4096;
        } else {
            g0 = W2b + (u - 16) * 1024;
            g1 = g0 + 512;
        }
        ASYNC16(g0, &stage[w][u & 3][0]);
        ASYNC16(g1, &stage[w][u & 3][512]);
    };

    // --- prologue: z0 = tanh(MLP(cov)) ---
    if (tid < 64) {
        float s = cb1[tid];
        for (int c = 0; c < 16; ++c) s += cov[b * 16 + c] * cw1[c * 64 + tid];
        ch[tid] = fmaxf(s, 0.f);
    }
    __syncthreads();
    if (tid < ZZ) {
        float v = cb2[tid];
        for (int j = 0; j < 64; ++j) v += ch[j] * cw2[j * ZZ + tid];
        v = fast_tanh(v);
        unsigned short hv = f2bf(v);
        for (int s = 0; s < SS; ++s) {
            zf[s][tid] = v;
            Az[s][tid] = hv;
            zhist[((size_t)b * SS + s) * ZZ + tid] = hv;   // slot 0
        }
    }

    float b2dr = 0.f;
    if (q < 2) b2dr = b2d[(w << 4) + l];

    issue(0); issue(1); issue(2);   // fill pipeline

    for (int t = 0; t < T_STEPS; ++t) {
        const size_t tb = (size_t)t * BB + b;

        // per-step scalars into registers (before barrier; overwait-safe)
        float eps[4], hppr[4], difr = 0.f;
        if (q < 2) {
            #pragma unroll
            for (int i = 0; i < 4; ++i)
                eps[i] = noise[((tb << 3) + (q << 2) + i) * ZZ + (w << 4) + l];
            #pragma unroll
            for (int ntl = 0; ntl < 4; ++ntl)
                hppr[ntl] = bf2f(HpprojQ[tb * HH + ((w << 2) + ntl) * 16 + l]);
            difr = DiffQ[tb * ZZ + (w << 4) + l];
        }
        __syncthreads();   // Az (prev normalize) ready; drains DMA queue too

        // ---- G1: hidden = relu(Hpp + z @ W1z), 16 slots
        f32x4 acc[4];
        {
            f32x4 z4 = {0.f, 0.f, 0.f, 0.f};
            #pragma unroll
            for (int ntl = 0; ntl < 4; ++ntl) acc[ntl] = z4;
        }
        bf16x8 afrag;
        #pragma unroll
        for (int u = 0; u < 16; ++u) {
            WAITVM(4);
            if (!(u & 1)) afrag = *(const bf16x8*)&Az[l & 7][(u >> 1) * 32 + (q << 3)];
            bf16x8 b0 = *(const bf16x8*)&stage[w][u & 3][0];
            bf16x8 b1 = *(const bf16x8*)&stage[w][u & 3][512];
            int p2 = (u & 1) << 1;
            acc[p2]     = MFMA(afrag, b0, acc[p2], 0, 0, 0);
            acc[p2 + 1] = MFMA(afrag, b1, acc[p2 + 1], 0, 0, 0);
            issue((u + 3) & 31);
        }
        if (q < 2) {
            #pragma unroll
            for (int ntl = 0; ntl < 4; ++ntl) {
                int n = (((w << 2) + ntl) << 4) + l;
                #pragma unroll
                for (int i = 0; i < 4; ++i)
                    Ah[(q << 2) + i][n] = f2bf(fmaxf(hppr[ntl] + acc[ntl][i], 0.f));
            }
        }
        __syncthreads();

        // ---- G2: drift_pre = hidden @ W2, 16 slots; z update
        f32x4 a2a = {0.f, 0.f, 0.f, 0.f};
        f32x4 a2b = {0.f, 0.f, 0.f, 0.f};
        #pragma unroll
        for (int u = 16; u < 32; ++u) {
            WAITVM(4);
            int kk = (u - 16) << 1;
            bf16x8 a0 = *(const bf16x8*)&Ah[l & 7][kk * 32 + (q << 3)];
            bf16x8 a1 = *(const bf16x8*)&Ah[l & 7][kk * 32 + 32 + (q << 3)];
            bf16x8 b0 = *(const bf16x8*)&stage[w][u & 3][0];
            bf16x8 b1 = *(const bf16x8*)&stage[w][u & 3][512];
            a2a = MFMA(a0, b0, a2a, 0, 0, 0);
            a2b = MFMA(a1, b1, a2b, 0, 0, 0);
            issue((u + 3) & 31);   // wraps into next step's G1 slots
        }
        if (q < 2) {
            int n = (w << 4) + l;
            #pragma unroll
            for (int i = 0; i < 4; ++i) {
                int s = (q << 2) + i;
                float pre = a2a[i] + a2b[i] + b2dr;
                float po = 0.1f * fast_tanh(pre);
                zf[s][n] += DT * po + SQRT_DT * difr * eps[i];
            }
        }
        __syncthreads();

        // ---- normalize (waves 0-7; wave s handles row s) + log zhist
        if (w < SS) {
            float v0 = zf[w][lane], v1 = zf[w][lane + 64];
            float v2 = zf[w][lane + 128], v3 = zf[w][lane + 192];
            float mn = fminf(fminf(v0, v1), fminf(v2, v3));
            float mx = fmaxf(fmaxf(v0, v1), fmaxf(v2, v3));
            for (int off = 32; off; off >>= 1) {
                mn = fminf(mn, __shfl_xor(mn, off, 64));
                mx = fmaxf(mx, __shfl_xor(mx, off, 64));
            }
            float sc = 1.0f / (mx - mn);
            v0 = (v0 - mn) * sc; v1 = (v1 - mn) * sc;
            v2 = (v2 - mn) * sc; v3 = (v3 - mn) * sc;
            zf[w][lane] = v0; zf[w][lane + 64] = v1;
            zf[w][lane + 128] = v2; zf[w][lane + 192] = v3;
            unsigned short h0 = f2bf(v0), h1 = f2bf(v1), h2 = f2bf(v2), h3 = f2bf(v3);
            Az[w][lane] = h0; Az[w][lane + 64] = h1;
            Az[w][lane + 128] = h2; Az[w][lane + 192] = h3;
            size_t zo = ((size_t)(t + 1) * BB + b) * (SS * ZZ) + (size_t)w * ZZ;
            zhist[zo + lane] = h0; zhist[zo + lane + 64] = h1;
            zhist[zo + lane + 128] = h2; zhist[zo + lane + 192] = h3;
        }
        // loop-top barrier separates Az writes from next G1 reads
    }
    __syncthreads();

    for (int idx = tid; idx < SS * ZZ; idx += 1024) {
        int s = idx >> 8, n = idx & 255;
        out[((size_t)b * SS + s) * ZZ + n] = zf[s][n];
    }
}

// ---------------------------------------------------------------------------
// Parallel post-pass 1: prior+poster drift recompute -> kld.
// ---------------------------------------------------------------------------
__global__ __launch_bounds__(512, 4)
void post_drift(const unsigned short* __restrict__ zhist,
                const unsigned short* __restrict__ HprojQ,
                const unsigned short* __restrict__ HpprojQ,
                const float* __restrict__ DiffQ, const float* __restrict__ b2d,
                const unsigned short* __restrict__ W1z_p,
                const unsigned short* __restrict__ W2_p,
                float* __restrict__ loss) {
    __shared__ unsigned short Az[4][16][ZZ + 8];
    __shared__ unsigned short Hp[2][4][16][136];
    __shared__ unsigned short ProjS[2][8][128];
    __shared__ float b2d_s[ZZ];
    __shared__ float red[8];
    const int tid = threadIdx.x;
    const int lane = tid & 63;
    const int w = tid >> 6;      // 8 waves
    const int q = lane >> 4;
    const int l = lane & 15;
    const int rt = w & 3;
    const int half = w >> 2;
    const int p0 = blockIdx.x << 3;   // first flat (t*B+b) pair

    for (int idx = tid; idx < 4096; idx += 512) {
        int r = idx >> 6, c4 = (idx & 63) << 2;
        *(ushort4*)&Az[r >> 4][r & 15][c4] =
            *(const ushort4*)&zhist[((size_t)p0 * SS + r) * ZZ + c4];
    }
    if (tid < ZZ) b2d_s[tid] = b2d[tid];

    f32x4 accP[8], accQ[8];
    {
        f32x4 z4 = {0.f, 0.f, 0.f, 0.f};
        #pragma unroll
        for (int j = 0; j < 8; ++j) { accP[j] = z4; accQ[j] = z4; }
    }

    for (int nc = 0; nc < 8; ++nc) {
        {
            int path = tid >> 8, rem = tid & 255;
            int pair = rem >> 5, c4 = (rem & 31) << 2;
            const unsigned short* src =
                (path ? HpprojQ : HprojQ) + (size_t)(p0 + pair) * HH + nc * 128 + c4;
            *(ushort4*)&ProjS[path][pair][c4] = *(const ushort4*)src;
        }
        __syncthreads();

        f32x4 za[4];
        {
            f32x4 z4 = {0.f, 0.f, 0.f, 0.f};
            #pragma unroll
            for (int j = 0; j < 4; ++j) za[j] = z4;
        }
        {
            const unsigned short* wb = W1z_p + lane * 8;
            bf16x8 wq[4];
            #pragma unroll
            for (int f = 0; f < 4; ++f) {
                int ks = f >> 2, j = f & 3;
                wq[f] = *(const bf16x8*)(wb +
                    ((size_t)((nc * 8 + half * 4 + j) * 8 + ks)) * 512);
            }
            #pragma unroll
            for (int f = 0; f < 32; ++f) {
                int ks = f >> 2, j = f & 3;
                bf16x8 a = *(const bf16x8*)&Az[rt][l][(ks << 5) + (q << 3)];
                za[j] = MFMA(a, wq[f & 3], za[j], 0, 0, 0);
                if (f < 28) {
                    int f2 = f + 4, ks2 = f2 >> 2, j2 = f2 & 3;
                    wq[f & 3] = *(const bf16x8*)(wb +
                        ((size_t)((nc * 8 + half * 4 + j2) * 8 + ks2)) * 512);
                }
            }
        }
        #pragma unroll
        for (int j = 0; j < 4; ++j) {
            int c = (half * 4 + j) * 16 + l;
            #pragma unroll
            for (int i = 0; i < 4; ++i) {
                int r = (q << 2) + i;
                int pair = ((rt << 4) + r) >> 3;
                float v = za[j][i];
                Hp[0][rt][r][c] = f2bf(fmaxf(bf2f(ProjS[0][pair][c]) + v, 0.f));
                Hp[1][rt][r][c] = f2bf(fmaxf(bf2f(ProjS[1][pair][c]) + v, 0.f));
            }
        }
        __syncthreads();

        {
            const unsigned short* wb2 = W2_p + lane * 8;
            bf16x8 wq2[4];
            #pragma unroll
            for (int f = 0; f < 4; ++f) {
                int kk = f >> 3, j = f & 7;
                wq2[f] = *(const bf16x8*)(wb2 +
                    ((size_t)((half * 8 + j) * 32 + nc * 4 + kk)) * 512);
            }
            #pragma unroll
            for (int f = 0; f < 32; ++f) {
                int kk = f >> 3, j = f & 7;
                bf16x8 aP = *(const bf16x8*)&Hp[0][rt][l][(kk << 5) + (q << 3)];
                bf16x8 aQ = *(const bf16x8*)&Hp[1][rt][l][(kk << 5) + (q << 3)];
                accP[j] = MFMA(aP, wq2[f & 3], accP[j], 0, 0, 0);
                accQ[j] = MFMA(aQ, wq2[f & 3], accQ[j], 0, 0, 0);
                if (f < 28) {
                    int f2 = f + 4, kk2 = f2 >> 3, j2 = f2 & 7;
                    wq2[f & 3] = *(const bf16x8*)(wb2 +
                        ((size_t)((half * 8 + j2) * 32 + nc * 4 + kk2)) * 512);
                }
            }
        }
        __syncthreads();
    }

    float kld_local = 0.f;
    #pragma unroll
    for (int j = 0; j < 8; ++j) {
        int n = ((half << 3) + j) * 16 + l;
        float bias = b2d_s[n];
        #pragma unroll
        for (int i = 0; i < 4; ++i) {
            int r = (rt << 4) + (q << 2) + i;
            int pair = p0 + (r >> 3);
            float pr = 0.1f * fast_tanh(accP[j][i] + bias);
            float po = 0.1f * fast_tanh(accQ[j][i] + bias);
            float e = (pr - po) / DiffQ[(size_t)pair * ZZ + n];
            kld_local += e * e;
        }
    }
    for (int off = 32; off; off >>= 1) kld_local += __shfl_down(kld_local, off, 64);
    if (lane == 0) red[w] = kld_local;
    __syncthreads();
    if (tid == 0) {
        float K = 0.f;
        for (int i = 0; i < 8; ++i) K += red[i];
        float kc = K * (0.5f * DT / (SS * BB));
        atomicAdd(loss + 0, kc);
        atomicAdd(loss + 2, kc);
    }
}

// ---------------------------------------------------------------------------
// Parallel post-pass 2: decoder on z_{t+1} -> recon.
// ---------------------------------------------------------------------------
__global__ __launch_bounds__(512, 4)
void post_dec(const unsigned short* __restrict__ zhist,
              const unsigned short* __restrict__ PprojQ,
              const float* __restrict__ X, const float* __restrict__ MtQ,
              const float* __restrict__ b2p,
              const unsigned short* __restrict__ PW1z_p,
              const unsigned short* __restrict__ PW2_p,
              float* __restrict__ loss) {
    __shared__ unsigned short Az[4][16][ZZ + 8];
    __shared__ unsigned short Hp[4][16][136];
    __shared__ unsigned short ProjS[8][128];
    __shared__ float b2p_s[DD];
    __shared__ float red[8];
    const int tid = threadIdx.x;
    const int lane = tid & 63;
    const int w = tid >> 6;
    const int q = lane >> 4;
    const int l = lane & 15;
    const int rt = w & 3;
    const int half = w >> 2;
    const int p0 = blockIdx.x << 3;

    for (int idx = tid; idx < 4096; idx += 512) {
        int r = idx >> 6, c4 = (idx & 63) << 2;
        *(ushort4*)&Az[r >> 4][r & 15][c4] =
            *(const ushort4*)&zhist[((size_t)(p0 + BB) * SS + r) * ZZ + c4];  // slot t+1
    }
    if (tid < DD) b2p_s[tid] = b2p[tid];

    f32x4 pacc[4];
    {
        f32x4 z4 = {0.f, 0.f, 0.f, 0.f};
        #pragma unroll
        for (int j = 0; j < 4; ++j) pacc[j] = z4;
    }

    for (int nc = 0; nc < 8; ++nc) {
        if (tid < 256) {
            int pair = tid >> 5, c4 = (tid & 31) << 2;
            *(ushort4*)&ProjS[pair][c4] =
                *(const ushort4*)&PprojQ[(size_t)(p0 + pair) * HH + nc * 128 + c4];
        }
        __syncthreads();

        f32x4 za[4];
        {
            f32x4 z4 = {0.f, 0.f, 0.f, 0.f};
            #pragma unroll
            for (int j = 0; j < 4; ++j) za[j] = z4;
        }
        {
            const unsigned short* wb = PW1z_p + lane * 8;
            bf16x8 wq[4];
            #pragma unroll
            for (int f = 0; f < 4; ++f) {
                int ks = f >> 2, j = f & 3;
                wq[f] = *(const bf16x8*)(wb +
                    ((size_t)((nc * 8 + half * 4 + j) * 8 + ks)) * 512);
            }
            #pragma unroll
            for (int f = 0; f < 32; ++f) {
                int ks = f >> 2, j = f & 3;
                bf16x8 a = *(const bf16x8*)&Az[rt][l][(ks << 5) + (q << 3)];
                za[j] = MFMA(a, wq[f & 3], za[j], 0, 0, 0);
                if (f < 28) {
                    int f2 = f + 4, ks2 = f2 >> 2, j2 = f2 & 3;
                    wq[f & 3] = *(const bf16x8*)(wb +
                        ((size_t)((nc * 8 + half * 4 + j2) * 8 + ks2)) * 512);
                }
            }
        }
        #pragma unroll
        for (int j = 0; j < 4; ++j) {
            int c = (half * 4 + j) * 16 + l;
            #pragma unroll
            for (int i = 0; i < 4; ++i) {
                int r = (q << 2) + i;
                int pair = ((rt << 4) + r) >> 3;
                Hp[rt][r][c] = f2bf(fmaxf(bf2f(ProjS[pair][c]) + za[j][i], 0.f));
            }
        }
        __syncthreads();

        {
            const unsigned short* wb2 = PW2_p + lane * 8;
            bf16x8 wq2[4];
            #pragma unroll
            for (int f = 0; f < 4; ++f) {
                int kk = f >> 2, j = f & 3;
                wq2[f] = *(const bf16x8*)(wb2 +
                    ((size_t)((half * 4 + j) * 32 + nc * 4 + kk)) * 512);
            }
            #pragma unroll
            for (int f = 0; f < 16; ++f) {
                int kk = f >> 2, j = f & 3;
                bf16x8 a = *(const bf16x8*)&Hp[rt][l][(kk << 5) + (q << 3)];
                pacc[j] = MFMA(a, wq2[f & 3], pacc[j], 0, 0, 0);
                if (f < 12) {
                    int f2 = f + 4, kk2 = f2 >> 2, j2 = f2 & 3;
                    wq2[f & 3] = *(const bf16x8*)(wb2 +
                        ((size_t)((half * 4 + j2) * 32 + nc * 4 + kk2)) * 512);
                }
            }
        }
        __syncthreads();
    }

    float rl = 0.f;
    #pragma unroll
    for (int j = 0; j < 4; ++j) {
        int n = ((half << 2) + j) * 16 + l;
        float bias = b2p_s[n];
        #pragma unroll
        for (int i = 0; i < 4; ++i) {
            int r = (rt << 4) + (q << 2) + i;
            int pair = p0 + (r >> 3);
            float p = pacc[j][i] + bias;
            float d = X[(size_t)pair * DD + n] - p;
            rl += (0.5f * (LOG2PIF + d * d)) * MtQ[pair];
        }
    }
    rl *= 1.0f / (SS * BB);
    for (int off = 32; off; off >>= 1) rl += __shfl_down(rl, off, 64);
    if (lane == 0) red[w] = rl;
    __syncthreads();
    if (tid == 0) {
        float R = 0.f;
        for (int i = 0; i < 8; ++i) R += red[i];
        atomicAdd(loss + 0, R);
        atomicAdd(loss + 1, R);
    }
}

extern "C" void kernel_launch(void* const* d_in, const int* in_sizes, int n_in,
                              void* d_out, int out_size, void* d_ws, size_t ws_size,
                              hipStream_t stream) {
    (void)in_sizes; (void)n_in; (void)ws_size;
    const float* X         = (const float*)d_in[0];
    const float* M         = (const float*)d_in[1];
    const float* cov       = (const float*)d_in[2];
    const float* path_h    = (const float*)d_in[3];
    const float* path_hpos = (const float*)d_in[4];
    const float* noise     = (const float*)d_in[5];
    const float* drift_w1  = (const float*)d_in[6];
    const float* drift_b1  = (const float*)d_in[7];
    const float* drift_w2  = (const float*)d_in[8];
    const float* drift_b2  = (const float*)d_in[9];
    const float* diff_w1   = (const float*)d_in[10];
    const float* diff_b1   = (const float*)d_in[11];
    const float* diff_w2   = (const float*)d_in[12];
    const float* diff_b2   = (const float*)d_in[13];
    const float* p_w1      = (const float*)d_in[14];
    const float* p_b1      = (const float*)d_in[15];
    const float* p_w2      = (const float*)d_in[16];
    const float* p_b2      = (const float*)d_in[17];
    const float* cov_w1    = (const float*)d_in[18];
    const float* cov_b1    = (const float*)d_in[19];
    const float* cov_w2    = (const float*)d_in[20];
    const float* cov_b2    = (const float*)d_in[21];

    char* ws = (char*)d_ws;
    size_t off = 0;
    auto alloc = [&](size_t bytes) {
        void* p = ws + off;
        off = (off + bytes + 255) & ~(size_t)255;
        return p;
    };
    unsigned short* HprojQ  = (unsigned short*)alloc((size_t)T_STEPS * BB * HH * 2);
    unsigned short* HpprojQ = (unsigned short*)alloc((size_t)T_STEPS * BB * HH * 2);
    unsigned short* PprojQ  = (unsigned short*)alloc((size_t)T_STEPS * BB * HH * 2);
    float*          DiffQ   = (float*)alloc((size_t)T_STEPS * BB * ZZ * 4);
    float*          MtQ     = (float*)alloc((size_t)T_STEPS * BB * 4);
    unsigned short* zhist   = (unsigned short*)alloc((size_t)(T_STEPS + 1) * BB * SS * ZZ * 2);
    unsigned short* W1z_p   = (unsigned short*)alloc((size_t)ZZ * HH * 2);
    unsigned short* W2_p    = (unsigned short*)alloc((size_t)HH * ZZ * 2);
    unsigned short* PW1z_p  = (unsigned short*)alloc((size_t)ZZ * HH * 2);
    unsigned short* PW2_p   = (unsigned short*)alloc((size_t)HH * DD * 2);
    unsigned short* W1h_p   = (unsigned short*)alloc((size_t)RR * HH * 2);
    unsigned short* PW1h_p  = (unsigned short*)alloc((size_t)RR * HH * 2);
    unsigned short* DW1_p   = (unsigned short*)alloc((size_t)RR * HH * 2);
    unsigned short* DW2_p   = (unsigned short*)alloc((size_t)HH * ZZ * 2);

    hipMemsetAsync(d_out, 0, (size_t)out_size * sizeof(float), stream);

    auto packLaunch = [&](const float* src, int K, int N, unsigned short* dst) {
        int total = (K / 32) * (N / 16) * 64;
        pack_w<<<(total + 255) / 256, 256, 0, stream>>>(src, K, N, dst);
    };
    packLaunch(drift_w1 + (size_t)RR * HH, ZZ, HH, W1z_p);
    packLaunch(drift_w2,                   HH, ZZ, W2_p);
    packLaunch(p_w1 + (size_t)RR * HH,     ZZ, HH, PW1z_p);
    packLaunch(p_w2,                       HH, DD, PW2_p);
    packLaunch(drift_w1, RR, HH, W1h_p);
    packLaunch(p_w1,     RR, HH, PW1h_p);
    packLaunch(diff_w1,  RR, HH, DW1_p);
    packLaunch(diff_w2,  HH, ZZ, DW2_p);

    mt_kernel<<<(T_STEPS * BB * 64) / 256, 256, 0, stream>>>(M, MtQ);

    precompute_kernel<<<(T_STEPS * BB) / 16, 256, 0, stream>>>(
        path_h, path_hpos, drift_b1, p_b1, diff_b1, diff_b2,
        W1h_p, PW1h_p, DW1_p, DW2_p, HprojQ, HpprojQ, PprojQ, DiffQ);

    float* outp = (float*)d_out;
    float* loss = outp + (size_t)BB * SS * ZZ;

    scan_kernel<<<BB, 1024, 0, stream>>>(
        cov, noise, drift_b2, cov_w1, cov_b1, cov_w2, cov_b2,
        W1z_p, W2_p, HpprojQ, DiffQ, zhist, outp);

    post_drift<<<(T_STEPS * BB) / 8, 512, 0, stream>>>(
        zhist, HprojQ, HpprojQ, DiffQ, drift_b2, W1z_p, W2_p, loss);

    post_dec<<<(T_STEPS * BB) / 8, 512, 0, stream>>>(
        zhist, PprojQ, X, MtQ, p_b2, PW1z_p, PW2_p, loss);
}

// Round 4
// 2904.508 us; speedup vs baseline: 4.2378x; 1.5573x over previous
//
#include <hip/hip_runtime.h>
#include <cstddef>
#include <cstdint>

#define T_STEPS 200
#define BB 64
#define SS 8
#define DD 128
#define RR 512
#define ZZ 256
#define HH 1024
#define DT 0.05f
#define SQRT_DT 0.22360679774997896f
#define LOG2PIF 1.8378770664093453f

typedef __attribute__((ext_vector_type(8))) short bf16x8;
typedef __attribute__((ext_vector_type(4))) float f32x4;
#define MFMA __builtin_amdgcn_mfma_f32_16x16x32_bf16

static __device__ __forceinline__ unsigned short f2bf(float x) {
    unsigned int u = __builtin_bit_cast(unsigned int, x);
    u += 0x7fffu + ((u >> 16) & 1u);
    return (unsigned short)(u >> 16);
}
static __device__ __forceinline__ float bf2f(unsigned short h) {
    unsigned int u = ((unsigned int)h) << 16;
    return __builtin_bit_cast(float, u);
}
static __device__ __forceinline__ float fast_tanh(float x) {
    float e = __expf(2.0f * x);
    return 1.0f - 2.0f / (e + 1.0f);
}

// Issue a 16B/lane load the compiler's waitcnt pass can't see.
static __device__ __forceinline__ void aload(bf16x8& d,
                                             const unsigned short* base, int off) {
    asm volatile("global_load_dwordx4 %0, %1, %2"
                 : "=v"(d) : "v"(off), "s"(base));
}
// Fence: frag v is ready once <=7 vmem ops are outstanding (depth-8 queue).
static __device__ __forceinline__ void vfence(bf16x8& v) {
    asm volatile("s_waitcnt vmcnt(7)" : "+v"(v));
}

// ---------------------------------------------------------------------------
// Pack row-major fp32 W[K][N] into bf16 MFMA B-fragment order:
// frag p = nt*(K/32)*64 + ks*64 + lane holds 8 elems: n = nt*16 + (lane&15),
// k = ks*32 + (lane>>4)*8 + i.
// ---------------------------------------------------------------------------
__global__ void pack_w(const float* __restrict__ src, int K, int N,
                       unsigned short* __restrict__ dst) {
    int total = (K >> 5) * (N >> 4) * 64;
    int p = blockIdx.x * blockDim.x + threadIdx.x;
    if (p >= total) return;
    int lane = p & 63;
    int ksteps = K >> 5;
    int ks = (p >> 6) % ksteps;
    int nt = p / (ksteps << 6);
    int n = (nt << 4) + (lane & 15);
    int k0 = (ks << 5) + ((lane >> 4) << 3);
    uint4 u4;
    unsigned short* tmp = reinterpret_cast<unsigned short*>(&u4);
    for (int i = 0; i < 8; ++i) tmp[i] = f2bf(src[(size_t)(k0 + i) * N + n]);
    *reinterpret_cast<uint4*>(dst + (size_t)p * 8) = u4;
}

// Mt[t,b] = mean over D of M[t,b,:]
__global__ void mt_kernel(const float* __restrict__ M, float* __restrict__ Mt) {
    int wv = (blockIdx.x * blockDim.x + threadIdx.x) >> 6;
    int lane = threadIdx.x & 63;
    if (wv >= T_STEPS * BB) return;
    const float* row = M + (size_t)wv * DD;
    float s = row[lane] + row[lane + 64];
    for (int off = 32; off; off >>= 1) s += __shfl_down(s, off, 64);
    if (lane == 0) Mt[wv] = s * (1.0f / DD);
}

// ---------------------------------------------------------------------------
// Precompute h-only projections (parallel over T*B, 16 rows/block).
// ---------------------------------------------------------------------------
#define PC_GEMM_1024(Asrc, Bp, biasArr, EMIT)                                    \
    {                                                                            \
        f32x4 acc[16];                                                           \
        f32x4 z4 = {0.f, 0.f, 0.f, 0.f};                                        \
        for (int ntl = 0; ntl < 16; ++ntl) acc[ntl] = z4;                        \
        for (int ks = 0; ks < 16; ++ks) {                                        \
            bf16x8 a = *(const bf16x8*)&Asrc[l][(ks << 5) + (q << 3)];           \
            for (int ntl = 0; ntl < 16; ++ntl) {                                 \
                int ntg = (w << 4) + ntl;                                        \
                bf16x8 bb = *(const bf16x8*)(Bp +                                \
                             (((size_t)ntg * 16 + ks) * 64 + lane) * 8);         \
                acc[ntl] = MFMA(a, bb, acc[ntl], 0, 0, 0);                       \
            }                                                                    \
        }                                                                        \
        for (int ntl = 0; ntl < 16; ++ntl) {                                     \
            int n = (((w << 4) + ntl) << 4) + l;                                 \
            float bv = biasArr[n];                                               \
            for (int i = 0; i < 4; ++i) {                                        \
                int rr = (q << 2) + i;                                           \
                float v = acc[ntl][i] + bv;                                      \
                EMIT;                                                            \
            }                                                                    \
        }                                                                        \
    }

__global__ __launch_bounds__(256)
void precompute_kernel(const float* __restrict__ h, const float* __restrict__ hpos,
                       const float* __restrict__ b1d, const float* __restrict__ b1p,
                       const float* __restrict__ b1f, const float* __restrict__ b2f,
                       const unsigned short* __restrict__ W1h_p,
                       const unsigned short* __restrict__ PW1h_p,
                       const unsigned short* __restrict__ DW1_p,
                       const unsigned short* __restrict__ DW2_p,
                       unsigned short* __restrict__ HprojQ,
                       unsigned short* __restrict__ HpprojQ,
                       unsigned short* __restrict__ PprojQ,
                       float* __restrict__ DiffQ) {
    __shared__ unsigned short Ahh[16][RR + 8];
    __shared__ unsigned short Ahp[16][RR + 8];
    __shared__ unsigned short Adh[16][HH + 8];
    const int tid = threadIdx.x;
    const int lane = tid & 63;
    const int w = tid >> 6;
    const int q = lane >> 4;
    const int l = lane & 15;
    const int r0 = blockIdx.x << 4;

    for (int idx = tid; idx < (RR << 4); idx += 256) {
        int r = idx >> 9, c = idx & (RR - 1);
        Ahh[r][c] = f2bf(h[(size_t)(r0 + r) * RR + c]);
        Ahp[r][c] = f2bf(hpos[(size_t)(r0 + r) * RR + c]);
    }
    __syncthreads();

    PC_GEMM_1024(Ahh, W1h_p,  b1d, (HprojQ [(size_t)(r0 + rr) * HH + n] = f2bf(v)));
    PC_GEMM_1024(Ahp, W1h_p,  b1d, (HpprojQ[(size_t)(r0 + rr) * HH + n] = f2bf(v)));
    PC_GEMM_1024(Ahh, PW1h_p, b1p, (PprojQ [(size_t)(r0 + rr) * HH + n] = f2bf(v)));
    PC_GEMM_1024(Ahh, DW1_p,  b1f, (Adh[rr][n] = f2bf(fmaxf(v, 0.f))));
    __syncthreads();

    {
        f32x4 acc[4];
        f32x4 z4 = {0.f, 0.f, 0.f, 0.f};
        for (int ntl = 0; ntl < 4; ++ntl) acc[ntl] = z4;
        for (int ks = 0; ks < 32; ++ks) {
            bf16x8 a = *(const bf16x8*)&Adh[l][(ks << 5) + (q << 3)];
            for (int ntl = 0; ntl < 4; ++ntl) {
                int ntg = (w << 2) + ntl;
                bf16x8 bb = *(const bf16x8*)(DW2_p +
                             (((size_t)ntg * 32 + ks) * 64 + lane) * 8);
                acc[ntl] = MFMA(a, bb, acc[ntl], 0, 0, 0);
            }
        }
        for (int ntl = 0; ntl < 4; ++ntl) {
            int n = (((w << 2) + ntl) << 4) + l;
            float bv = b2f[n];
            for (int i = 0; i < 4; ++i) {
                int rr = (q << 2) + i;
                DiffQ[(size_t)(r0 + rr) * ZZ + n] = __expf(acc[ntl][i] + bv);
            }
        }
    }
}

// ---------------------------------------------------------------------------
// Sequential scan, posterior path only. 64 blocks x 1024 thr (16 waves).
// Weight B-fragments streamed into depth-8 VGPR queues via inline-asm
// global_load_dwordx4 + manual vmcnt(7) fences (invisible to the compiler's
// waitcnt pass -> no forced drains). Cross-stage/cross-step prefetch in the
// loop tails; barriers merely complete in-flight loads (regs keep the data).
// ---------------------------------------------------------------------------
__global__ __launch_bounds__(1024)
void scan_kernel(const float* __restrict__ cov, const float* __restrict__ noise,
                 const float* __restrict__ b2d,
                 const float* __restrict__ cw1, const float* __restrict__ cb1,
                 const float* __restrict__ cw2, const float* __restrict__ cb2,
                 const unsigned short* __restrict__ W1z_p,
                 const unsigned short* __restrict__ W2_p,
                 const unsigned short* __restrict__ HpprojQ,
                 const float* __restrict__ DiffQ,
                 unsigned short* __restrict__ zhist,
                 float* __restrict__ out) {
    __shared__ __align__(16) unsigned short Az[8][264];    // z bf16 (8 rows)
    __shared__ __align__(16) unsigned short Ah[8][1040];   // poster hidden
    __shared__ float zf[8][256];                           // fp32 master z
    __shared__ float ch[64];

    const int tid = threadIdx.x;
    const int lane = tid & 63;
    const int w = tid >> 6;   // 16 waves
    const int q = lane >> 4;
    const int l = lane & 15;
    const int b = blockIdx.x;

    // shared per-wave byte offset into both packed weight streams
    const int baseoff = (w << 15) + lane * 16;
    // G1 frag j (j=ks*4+ntl): baseoff + ntl*8192 + ks*1024
    // G2 frag j (j=kk):       baseoff + kk*1024

    // --- prologue: z0 = tanh(MLP(cov)) ---
    if (tid < 64) {
        float s = cb1[tid];
        for (int c = 0; c < 16; ++c) s += cov[b * 16 + c] * cw1[c * 64 + tid];
        ch[tid] = fmaxf(s, 0.f);
    }
    __syncthreads();
    if (tid < ZZ) {
        float v = cb2[tid];
        for (int j = 0; j < 64; ++j) v += ch[j] * cw2[j * ZZ + tid];
        v = fast_tanh(v);
        unsigned short hv = f2bf(v);
        for (int s = 0; s < SS; ++s) {
            zf[s][tid] = v;
            Az[s][tid] = hv;
            zhist[((size_t)b * SS + s) * ZZ + tid] = hv;   // slot 0
        }
    }

    float b2dr = 0.f;
    if (q < 2) b2dr = b2d[(w << 4) + l];

    // preload G1 frags 0..7 for t=0
    bf16x8 fq[8];
    #pragma unroll
    for (int j = 0; j < 8; ++j)
        aload(fq[j], W1z_p, baseoff + (j & 3) * 8192 + (j >> 2) * 1024);

    for (int t = 0; t < T_STEPS; ++t) {
        const size_t tb = (size_t)t * BB + b;

        // per-step scalars (all lanes; upper half duplicates) — pinned complete
        float eps[4], hppr[4], difr;
        const int sq = q & 1;
        #pragma unroll
        for (int i = 0; i < 4; ++i)
            eps[i] = noise[((tb << 3) + (sq << 2) + i) * ZZ + (w << 4) + l];
        #pragma unroll
        for (int ntl = 0; ntl < 4; ++ntl)
            hppr[ntl] = bf2f(HpprojQ[tb * HH + ((w << 2) + ntl) * 16 + l]);
        difr = DiffQ[tb * ZZ + (w << 4) + l];
        asm volatile("" :: "v"(eps[0]), "v"(eps[1]), "v"(eps[2]), "v"(eps[3]),
                           "v"(hppr[0]), "v"(hppr[1]), "v"(hppr[2]), "v"(hppr[3]),
                           "v"(difr));
        __syncthreads();   // Az from prev normalize ready; vmem queue drains

        // ---- G1: hidden = relu(Hpp + z @ W1z); 32 frags, tail prefetches G2
        f32x4 acc1[4];
        {
            f32x4 z4 = {0.f, 0.f, 0.f, 0.f};
            #pragma unroll
            for (int ntl = 0; ntl < 4; ++ntl) acc1[ntl] = z4;
        }
        bf16x8 a1;
        #pragma unroll
        for (int j = 0; j < 32; ++j) {
            const int ks = j >> 2, ntl = j & 3;
            vfence(fq[j & 7]);
            if (ntl == 0) a1 = *(const bf16x8*)&Az[l & 7][ks * 32 + (q << 3)];
            acc1[ntl] = MFMA(a1, fq[j & 7], acc1[ntl], 0, 0, 0);
            if (j < 24) {
                const int j2 = j + 8;
                aload(fq[j & 7], W1z_p, baseoff + (j2 & 3) * 8192 + (j2 >> 2) * 1024);
            } else {
                aload(fq[j & 7], W2_p, baseoff + (j - 24) * 1024);
            }
        }
        if (q < 2) {
            #pragma unroll
            for (int ntl = 0; ntl < 4; ++ntl) {
                int n = (((w << 2) + ntl) << 4) + l;
                #pragma unroll
                for (int i = 0; i < 4; ++i)
                    Ah[(q << 2) + i][n] = f2bf(fmaxf(hppr[ntl] + acc1[ntl][i], 0.f));
            }
        }
        __syncthreads();

        // ---- G2: drift_pre = hidden @ W2; 32 frags, tail prefetches next G1
        f32x4 a2a = {0.f, 0.f, 0.f, 0.f};
        f32x4 a2b = {0.f, 0.f, 0.f, 0.f};
        #pragma unroll
        for (int j = 0; j < 32; ++j) {
            vfence(fq[j & 7]);
            bf16x8 a2 = *(const bf16x8*)&Ah[l & 7][j * 32 + (q << 3)];
            if (j & 1) a2b = MFMA(a2, fq[j & 7], a2b, 0, 0, 0);
            else       a2a = MFMA(a2, fq[j & 7], a2a, 0, 0, 0);
            if (j < 24) {
                aload(fq[j & 7], W2_p, baseoff + (j + 8) * 1024);
            } else {
                const int j2 = j - 24;
                aload(fq[j & 7], W1z_p, baseoff + (j2 & 3) * 8192 + (j2 >> 2) * 1024);
            }
        }
        if (q < 2) {
            int n = (w << 4) + l;
            #pragma unroll
            for (int i = 0; i < 4; ++i) {
                int s = (q << 2) + i;
                float pre = a2a[i] + a2b[i] + b2dr;
                float po = 0.1f * fast_tanh(pre);
                zf[s][n] += DT * po + SQRT_DT * difr * eps[i];
            }
        }
        __syncthreads();

        // ---- normalize (waves 0-7; wave s handles row s) + log zhist
        if (w < SS) {
            float v0 = zf[w][lane], v1 = zf[w][lane + 64];
            float v2 = zf[w][lane + 128], v3 = zf[w][lane + 192];
            float mn = fminf(fminf(v0, v1), fminf(v2, v3));
            float mx = fmaxf(fmaxf(v0, v1), fmaxf(v2, v3));
            for (int off = 32; off; off >>= 1) {
                mn = fminf(mn, __shfl_xor(mn, off, 64));
                mx = fmaxf(mx, __shfl_xor(mx, off, 64));
            }
            float sc = 1.0f / (mx - mn);
            v0 = (v0 - mn) * sc; v1 = (v1 - mn) * sc;
            v2 = (v2 - mn) * sc; v3 = (v3 - mn) * sc;
            zf[w][lane] = v0; zf[w][lane + 64] = v1;
            zf[w][lane + 128] = v2; zf[w][lane + 192] = v3;
            unsigned short h0 = f2bf(v0), h1 = f2bf(v1), h2 = f2bf(v2), h3 = f2bf(v3);
            Az[w][lane] = h0; Az[w][lane + 64] = h1;
            Az[w][lane + 128] = h2; Az[w][lane + 192] = h3;
            size_t zo = ((size_t)(t + 1) * BB + b) * (SS * ZZ) + (size_t)w * ZZ;
            volatile unsigned short* zh = (volatile unsigned short*)zhist;
            zh[zo + lane] = h0; zh[zo + lane + 64] = h1;
            zh[zo + lane + 128] = h2; zh[zo + lane + 192] = h3;
        }
        // loop-top barrier separates Az writes from next G1 reads
    }
    __syncthreads();

    for (int idx = tid; idx < SS * ZZ; idx += 1024) {
        int s = idx >> 8, n = idx & 255;
        out[((size_t)b * SS + s) * ZZ + n] = zf[s][n];
    }
}

// ---------------------------------------------------------------------------
// Parallel post-pass 1: prior+poster drift recompute -> kld.
// ---------------------------------------------------------------------------
__global__ __launch_bounds__(512, 4)
void post_drift(const unsigned short* __restrict__ zhist,
                const unsigned short* __restrict__ HprojQ,
                const unsigned short* __restrict__ HpprojQ,
                const float* __restrict__ DiffQ, const float* __restrict__ b2d,
                const unsigned short* __restrict__ W1z_p,
                const unsigned short* __restrict__ W2_p,
                float* __restrict__ loss) {
    __shared__ unsigned short Az[4][16][ZZ + 8];
    __shared__ unsigned short Hp[2][4][16][136];
    __shared__ unsigned short ProjS[2][8][128];
    __shared__ float b2d_s[ZZ];
    __shared__ float red[8];
    const int tid = threadIdx.x;
    const int lane = tid & 63;
    const int w = tid >> 6;      // 8 waves
    const int q = lane >> 4;
    const int l = lane & 15;
    const int rt = w & 3;
    const int half = w >> 2;
    const int p0 = blockIdx.x << 3;   // first flat (t*B+b) pair

    for (int idx = tid; idx < 4096; idx += 512) {
        int r = idx >> 6, c4 = (idx & 63) << 2;
        *(ushort4*)&Az[r >> 4][r & 15][c4] =
            *(const ushort4*)&zhist[((size_t)p0 * SS + r) * ZZ + c4];
    }
    if (tid < ZZ) b2d_s[tid] = b2d[tid];

    f32x4 accP[8], accQ[8];
    {
        f32x4 z4 = {0.f, 0.f, 0.f, 0.f};
        #pragma unroll
        for (int j = 0; j < 8; ++j) { accP[j] = z4; accQ[j] = z4; }
    }

    for (int nc = 0; nc < 8; ++nc) {
        {
            int path = tid >> 8, rem = tid & 255;
            int pair = rem >> 5, c4 = (rem & 31) << 2;
            const unsigned short* src =
                (path ? HpprojQ : HprojQ) + (size_t)(p0 + pair) * HH + nc * 128 + c4;
            *(ushort4*)&ProjS[path][pair][c4] = *(const ushort4*)src;
        }
        __syncthreads();

        f32x4 za[4];
        {
            f32x4 z4 = {0.f, 0.f, 0.f, 0.f};
            #pragma unroll
            for (int j = 0; j < 4; ++j) za[j] = z4;
        }
        {
            const unsigned short* wb = W1z_p + lane * 8;
            bf16x8 wq[4];
            #pragma unroll
            for (int f = 0; f < 4; ++f) {
                int ks = f >> 2, j = f & 3;
                wq[f] = *(const bf16x8*)(wb +
                    ((size_t)((nc * 8 + half * 4 + j) * 8 + ks)) * 512);
            }
            #pragma unroll
            for (int f = 0; f < 32; ++f) {
                int ks = f >> 2, j = f & 3;
                bf16x8 a = *(const bf16x8*)&Az[rt][l][(ks << 5) + (q << 3)];
                za[j] = MFMA(a, wq[f & 3], za[j], 0, 0, 0);
                if (f < 28) {
                    int f2 = f + 4, ks2 = f2 >> 2, j2 = f2 & 3;
                    wq[f & 3] = *(const bf16x8*)(wb +
                        ((size_t)((nc * 8 + half * 4 + j2) * 8 + ks2)) * 512);
                }
            }
        }
        #pragma unroll
        for (int j = 0; j < 4; ++j) {
            int c = (half * 4 + j) * 16 + l;
            #pragma unroll
            for (int i = 0; i < 4; ++i) {
                int r = (q << 2) + i;
                int pair = ((rt << 4) + r) >> 3;
                float v = za[j][i];
                Hp[0][rt][r][c] = f2bf(fmaxf(bf2f(ProjS[0][pair][c]) + v, 0.f));
                Hp[1][rt][r][c] = f2bf(fmaxf(bf2f(ProjS[1][pair][c]) + v, 0.f));
            }
        }
        __syncthreads();

        {
            const unsigned short* wb2 = W2_p + lane * 8;
            bf16x8 wq2[4];
            #pragma unroll
            for (int f = 0; f < 4; ++f) {
                int kk = f >> 3, j = f & 7;
                wq2[f] = *(const bf16x8*)(wb2 +
                    ((size_t)((half * 8 + j) * 32 + nc * 4 + kk)) * 512);
            }
            #pragma unroll
            for (int f = 0; f < 32; ++f) {
                int kk = f >> 3, j = f & 7;
                bf16x8 aP = *(const bf16x8*)&Hp[0][rt][l][(kk << 5) + (q << 3)];
                bf16x8 aQ = *(const bf16x8*)&Hp[1][rt][l][(kk << 5) + (q << 3)];
                accP[j] = MFMA(aP, wq2[f & 3], accP[j], 0, 0, 0);
                accQ[j] = MFMA(aQ, wq2[f & 3], accQ[j], 0, 0, 0);
                if (f < 28) {
                    int f2 = f + 4, kk2 = f2 >> 3, j2 = f2 & 7;
                    wq2[f & 3] = *(const bf16x8*)(wb2 +
                        ((size_t)((half * 8 + j2) * 32 + nc * 4 + kk2)) * 512);
                }
            }
        }
        __syncthreads();
    }

    float kld_local = 0.f;
    #pragma unroll
    for (int j = 0; j < 8; ++j) {
        int n = ((half << 3) + j) * 16 + l;
        float bias = b2d_s[n];
        #pragma unroll
        for (int i = 0; i < 4; ++i) {
            int r = (rt << 4) + (q << 2) + i;
            int pair = p0 + (r >> 3);
            float pr = 0.1f * fast_tanh(accP[j][i] + bias);
            float po = 0.1f * fast_tanh(accQ[j][i] + bias);
            float e = (pr - po) / DiffQ[(size_t)pair * ZZ + n];
            kld_local += e * e;
        }
    }
    for (int off = 32; off; off >>= 1) kld_local += __shfl_down(kld_local, off, 64);
    if (lane == 0) red[w] = kld_local;
    __syncthreads();
    if (tid == 0) {
        float K = 0.f;
        for (int i = 0; i < 8; ++i) K += red[i];
        float kc = K * (0.5f * DT / (SS * BB));
        atomicAdd(loss + 0, kc);
        atomicAdd(loss + 2, kc);
    }
}

// ---------------------------------------------------------------------------
// Parallel post-pass 2: decoder on z_{t+1} -> recon.
// ---------------------------------------------------------------------------
__global__ __launch_bounds__(512, 4)
void post_dec(const unsigned short* __restrict__ zhist,
              const unsigned short* __restrict__ PprojQ,
              const float* __restrict__ X, const float* __restrict__ MtQ,
              const float* __restrict__ b2p,
              const unsigned short* __restrict__ PW1z_p,
              const unsigned short* __restrict__ PW2_p,
              float* __restrict__ loss) {
    __shared__ unsigned short Az[4][16][ZZ + 8];
    __shared__ unsigned short Hp[4][16][136];
    __shared__ unsigned short ProjS[8][128];
    __shared__ float b2p_s[DD];
    __shared__ float red[8];
    const int tid = threadIdx.x;
    const int lane = tid & 63;
    const int w = tid >> 6;
    const int q = lane >> 4;
    const int l = lane & 15;
    const int rt = w & 3;
    const int half = w >> 2;
    const int p0 = blockIdx.x << 3;

    for (int idx = tid; idx < 4096; idx += 512) {
        int r = idx >> 6, c4 = (idx & 63) << 2;
        *(ushort4*)&Az[r >> 4][r & 15][c4] =
            *(const ushort4*)&zhist[((size_t)(p0 + BB) * SS + r) * ZZ + c4];  // slot t+1
    }
    if (tid < DD) b2p_s[tid] = b2p[tid];

    f32x4 pacc[4];
    {
        f32x4 z4 = {0.f, 0.f, 0.f, 0.f};
        #pragma unroll
        for (int j = 0; j < 4; ++j) pacc[j] = z4;
    }

    for (int nc = 0; nc < 8; ++nc) {
        if (tid < 256) {
            int pair = tid >> 5, c4 = (tid & 31) << 2;
            *(ushort4*)&ProjS[pair][c4] =
                *(const ushort4*)&PprojQ[(size_t)(p0 + pair) * HH + nc * 128 + c4];
        }
        __syncthreads();

        f32x4 za[4];
        {
            f32x4 z4 = {0.f, 0.f, 0.f, 0.f};
            #pragma unroll
            for (int j = 0; j < 4; ++j) za[j] = z4;
        }
        {
            const unsigned short* wb = PW1z_p + lane * 8;
            bf16x8 wq[4];
            #pragma unroll
            for (int f = 0; f < 4; ++f) {
                int ks = f >> 2, j = f & 3;
                wq[f] = *(const bf16x8*)(wb +
                    ((size_t)((nc * 8 + half * 4 + j) * 8 + ks)) * 512);
            }
            #pragma unroll
            for (int f = 0; f < 32; ++f) {
                int ks = f >> 2, j = f & 3;
                bf16x8 a = *(const bf16x8*)&Az[rt][l][(ks << 5) + (q << 3)];
                za[j] = MFMA(a, wq[f & 3], za[j], 0, 0, 0);
                if (f < 28) {
                    int f2 = f + 4, ks2 = f2 >> 2, j2 = f2 & 3;
                    wq[f & 3] = *(const bf16x8*)(wb +
                        ((size_t)((nc * 8 + half * 4 + j2) * 8 + ks2)) * 512);
                }
            }
        }
        #pragma unroll
        for (int j = 0; j < 4; ++j) {
            int c = (half * 4 + j) * 16 + l;
            #pragma unroll
            for (int i = 0; i < 4; ++i) {
                int r = (q << 2) + i;
                int pair = ((rt << 4) + r) >> 3;
                Hp[rt][r][c] = f2bf(fmaxf(bf2f(ProjS[pair][c]) + za[j][i], 0.f));
            }
        }
        __syncthreads();

        {
            const unsigned short* wb2 = PW2_p + lane * 8;
            bf16x8 wq2[4];
            #pragma unroll
            for (int f = 0; f < 4; ++f) {
                int kk = f >> 2, j = f & 3;
                wq2[f] = *(const bf16x8*)(wb2 +
                    ((size_t)((half * 4 + j) * 32 + nc * 4 + kk)) * 512);
            }
            #pragma unroll
            for (int f = 0; f < 16; ++f) {
                int kk = f >> 2, j = f & 3;
                bf16x8 a = *(const bf16x8*)&Hp[rt][l][(kk << 5) + (q << 3)];
                pacc[j] = MFMA(a, wq2[f & 3], pacc[j], 0, 0, 0);
                if (f < 12) {
                    int f2 = f + 4, kk2 = f2 >> 2, j2 = f2 & 3;
                    wq2[f & 3] = *(const bf16x8*)(wb2 +
                        ((size_t)((half * 4 + j2) * 32 + nc * 4 + kk2)) * 512);
                }
            }
        }
        __syncthreads();
    }

    float rl = 0.f;
    #pragma unroll
    for (int j = 0; j < 4; ++j) {
        int n = ((half << 2) + j) * 16 + l;
        float bias = b2p_s[n];
        #pragma unroll
        for (int i = 0; i < 4; ++i) {
            int r = (rt << 4) + (q << 2) + i;
            int pair = p0 + (r >> 3);
            float p = pacc[j][i] + bias;
            float d = X[(size_t)pair * DD + n] - p;
            rl += (0.5f * (LOG2PIF + d * d)) * MtQ[pair];
        }
    }
    rl *= 1.0f / (SS * BB);
    for (int off = 32; off; off >>= 1) rl += __shfl_down(rl, off, 64);
    if (lane == 0) red[w] = rl;
    __syncthreads();
    if (tid == 0) {
        float R = 0.f;
        for (int i = 0; i < 8; ++i) R += red[i];
        atomicAdd(loss + 0, R);
        atomicAdd(loss + 1, R);
    }
}

extern "C" void kernel_launch(void* const* d_in, const int* in_sizes, int n_in,
                              void* d_out, int out_size, void* d_ws, size_t ws_size,
                              hipStream_t stream) {
    (void)in_sizes; (void)n_in; (void)ws_size;
    const float* X         = (const float*)d_in[0];
    const float* M         = (const float*)d_in[1];
    const float* cov       = (const float*)d_in[2];
    const float* path_h    = (const float*)d_in[3];
    const float* path_hpos = (const float*)d_in[4];
    const float* noise     = (const float*)d_in[5];
    const float* drift_w1  = (const float*)d_in[6];
    const float* drift_b1  = (const float*)d_in[7];
    const float* drift_w2  = (const float*)d_in[8];
    const float* drift_b2  = (const float*)d_in[9];
    const float* diff_w1   = (const float*)d_in[10];
    const float* diff_b1   = (const float*)d_in[11];
    const float* diff_w2   = (const float*)d_in[12];
    const float* diff_b2   = (const float*)d_in[13];
    const float* p_w1      = (const float*)d_in[14];
    const float* p_b1      = (const float*)d_in[15];
    const float* p_w2      = (const float*)d_in[16];
    const float* p_b2      = (const float*)d_in[17];
    const float* cov_w1    = (const float*)d_in[18];
    const float* cov_b1    = (const float*)d_in[19];
    const float* cov_w2    = (const float*)d_in[20];
    const float* cov_b2    = (const float*)d_in[21];

    char* ws = (char*)d_ws;
    size_t off = 0;
    auto alloc = [&](size_t bytes) {
        void* p = ws + off;
        off = (off + bytes + 255) & ~(size_t)255;
        return p;
    };
    unsigned short* HprojQ  = (unsigned short*)alloc((size_t)T_STEPS * BB * HH * 2);
    unsigned short* HpprojQ = (unsigned short*)alloc((size_t)T_STEPS * BB * HH * 2);
    unsigned short* PprojQ  = (unsigned short*)alloc((size_t)T_STEPS * BB * HH * 2);
    float*          DiffQ   = (float*)alloc((size_t)T_STEPS * BB * ZZ * 4);
    float*          MtQ     = (float*)alloc((size_t)T_STEPS * BB * 4);
    unsigned short* zhist   = (unsigned short*)alloc((size_t)(T_STEPS + 1) * BB * SS * ZZ * 2);
    unsigned short* W1z_p   = (unsigned short*)alloc((size_t)ZZ * HH * 2);
    unsigned short* W2_p    = (unsigned short*)alloc((size_t)HH * ZZ * 2);
    unsigned short* PW1z_p  = (unsigned short*)alloc((size_t)ZZ * HH * 2);
    unsigned short* PW2_p   = (unsigned short*)alloc((size_t)HH * DD * 2);
    unsigned short* W1h_p   = (unsigned short*)alloc((size_t)RR * HH * 2);
    unsigned short* PW1h_p  = (unsigned short*)alloc((size_t)RR * HH * 2);
    unsigned short* DW1_p   = (unsigned short*)alloc((size_t)RR * HH * 2);
    unsigned short* DW2_p   = (unsigned short*)alloc((size_t)HH * ZZ * 2);

    hipMemsetAsync(d_out, 0, (size_t)out_size * sizeof(float), stream);

    auto packLaunch = [&](const float* src, int K, int N, unsigned short* dst) {
        int total = (K / 32) * (N / 16) * 64;
        pack_w<<<(total + 255) / 256, 256, 0, stream>>>(src, K, N, dst);
    };
    packLaunch(drift_w1 + (size_t)RR * HH, ZZ, HH, W1z_p);
    packLaunch(drift_w2,                   HH, ZZ, W2_p);
    packLaunch(p_w1 + (size_t)RR * HH,     ZZ, HH, PW1z_p);
    packLaunch(p_w2,                       HH, DD, PW2_p);
    packLaunch(drift_w1, RR, HH, W1h_p);
    packLaunch(p_w1,     RR, HH, PW1h_p);
    packLaunch(diff_w1,  RR, HH, DW1_p);
    packLaunch(diff_w2,  HH, ZZ, DW2_p);

    mt_kernel<<<(T_STEPS * BB * 64) / 256, 256, 0, stream>>>(M, MtQ);

    precompute_kernel<<<(T_STEPS * BB) / 16, 256, 0, stream>>>(
        path_h, path_hpos, drift_b1, p_b1, diff_b1, diff_b2,
        W1h_p, PW1h_p, DW1_p, DW2_p, HprojQ, HpprojQ, PprojQ, DiffQ);

    float* outp = (float*)d_out;
    float* loss = outp + (size_t)BB * SS * ZZ;

    scan_kernel<<<BB, 1024, 0, stream>>>(
        cov, noise, drift_b2, cov_w1, cov_b1, cov_w2, cov_b2,
        W1z_p, W2_p, HpprojQ, DiffQ, zhist, outp);

    post_drift<<<(T_STEPS * BB) / 8, 512, 0, stream>>>(
        zhist, HprojQ, HpprojQ, DiffQ, drift_b2, W1z_p, W2_p, loss);

    post_dec<<<(T_STEPS * BB) / 8, 512, 0, stream>>>(
        zhist, PprojQ, X, MtQ, p_b2, PW1z_p, PW2_p, loss);
}